// Round 8
// baseline (673.313 us; speedup 1.0000x reference)
//
#include <hip/hip_runtime.h>
#include <cfloat>
#include <cmath>

#define NROWS 65536
#define DDIM 256
#define KDIM 4096

typedef short bf16x8 __attribute__((ext_vector_type(8)));
typedef float f32x4 __attribute__((ext_vector_type(4)));

constexpr float EPSV = 1e-5f;
constexpr float DECAYV = 0.99f;
constexpr float MOMV = 0.1f;
constexpr float DELTA = 1.0f;   // bf16 noise (~0.4) + pack trunc (0.25) + slack
constexpr int CAP = 16;
constexpr int SEG = 128;        // rows per gather segment

// ---------------- workspace layout (float offsets) ----------------
constexpr size_t WS_CNT     = 0;                               // int[N] cand counts (zeroed)
constexpr size_t WS_NFLAG   = WS_CNT + NROWS;                  // int[1]+pad (zeroed)
constexpr size_t WS_HIST    = WS_NFLAG + 64;                   // int[K] (zeroed)
constexpr size_t WS_ZEND    = WS_HIST + KDIM;                  // end of zeroed region
constexpr size_t WS_START   = WS_ZEND;                         // int[K]
constexpr size_t WS_FILLPOS = WS_START + KDIM;                 // int[K]
constexpr size_t WS_SEGSTART= WS_FILLPOS + KDIM;               // int[K+64]
constexpr size_t WS_NSEG    = WS_SEGSTART + KDIM + 64;         // int[1]+pad
constexpr size_t WS_SEGLIST = WS_NSEG + 64;                    // int[4608+pad]
constexpr size_t WS_PARTSUM = WS_SEGLIST + 4672;               // [2048][256]
constexpr size_t WS_PARTSQ  = WS_PARTSUM + 2048 * DDIM;        // [2048][256]
constexpr size_t WS_MIDSUM  = WS_PARTSQ + 2048 * DDIM;         // [256][256]
constexpr size_t WS_MIDSQ   = WS_MIDSUM + 256 * DDIM;          // [256][256]
constexpr size_t WS_MEAN    = WS_MIDSQ + 256 * DDIM;           // [256]
constexpr size_t WS_RSTD    = WS_MEAN + DDIM;                  // [256]
constexpr size_t WS_NRMEAN  = WS_RSTD + DDIM;                  // [256]
constexpr size_t WS_NRVAR   = WS_NRMEAN + DDIM;                // [256]
constexpr size_t WS_BVEC    = WS_NRVAR + DDIM;                 // [4096]
constexpr size_t WS_NCSRAW  = WS_BVEC + KDIM;                  // [4096]
constexpr size_t WS_NTOT    = WS_NCSRAW + KDIM;                // [1]+pad
constexpr size_t WS_ROWINFO = WS_NTOT + 64;                    // float2[N][4] packed (v1,v2)
constexpr size_t WS_IDX     = WS_ROWINFO + 8 * (size_t)NROWS;  // int[N]
constexpr size_t WS_ROWTHR  = WS_IDX + NROWS;                  // float[N]
constexpr size_t WS_FLAG    = WS_ROWTHR + NROWS;               // int[N]
constexpr size_t WS_ROWLIST = WS_FLAG + NROWS;                 // int[N]
constexpr size_t WS_CAND    = WS_ROWLIST + NROWS;              // int[N*CAP]
constexpr size_t WS_DWPART  = WS_CAND;                         // ALIAS: float[4608][256] over CAND+EPROW (dead by then)
constexpr size_t WS_EPROW   = WS_CAND + (size_t)NROWS * CAP;   // float[K][D]
constexpr size_t WS_EIMG    = WS_EPROW + (size_t)KDIM * DDIM;  // bf16 E image 2MB
constexpr size_t WS_XIMG    = WS_EIMG + 524288;                // bf16 X image 32MB

// ---------------- output layout (float offsets) ----------------
constexpr size_t O_IDX   = 0;
constexpr size_t O_EMB   = NROWS;
constexpr size_t O_EOUT  = O_EMB + (size_t)KDIM * DDIM;
constexpr size_t O_CS    = O_EOUT + (size_t)KDIM * DDIM;
constexpr size_t O_EMAW  = O_CS + KDIM;
constexpr size_t O_RMEAN = O_EMAW + (size_t)KDIM * DDIM;
constexpr size_t O_RVAR  = O_RMEAN + DDIM;

__device__ inline unsigned bfpack(float a, float b) {   // RNE f32->bf16 pair
    unsigned ua = __float_as_uint(a), ub = __float_as_uint(b);
    ua = (ua + 0x7FFFu + ((ua >> 16) & 1u)) >> 16;
    ub = (ub + 0x7FFFu + ((ub >> 16) & 1u)) & 0xFFFF0000u;
    return (ua & 0xFFFFu) | ub;
}

__device__ inline float unpackval(float p) {            // strip idx bits -> value
    return __uint_as_float(__float_as_uint(p) & 0xFFFFF000u);
}

#define GLOAD_LDS16(g, l) __builtin_amdgcn_global_load_lds(                       \
        (const __attribute__((address_space(1))) void*)(g),                        \
        (__attribute__((address_space(3))) void*)(l), 16, 0, 0)

// ===== K1: BN partial sums + fused x -> bf16 rotated image (float4) =====
// 512 blocks x 256 thr: 4 row-groups x 64 d-quads, 32 rows per group.
__global__ __launch_bounds__(256) void k_bnpack(const float* __restrict__ x,
                                                float* __restrict__ ws) {
    const int t = threadIdx.x;
    const int q = t & 63, g = t >> 6;
    const int r0 = blockIdx.x * 128 + g * 32;
    char* ximg = (char*)(ws + WS_XIMG);
    const float4* x4 = (const float4*)x;
    float4 s = make_float4(0.f, 0.f, 0.f, 0.f);
    float4 sq = make_float4(0.f, 0.f, 0.f, 0.f);
#pragma unroll 4
    for (int i = 0; i < 32; ++i) {
        const int r = r0 + i;
        const float4 v = x4[(size_t)r * 64 + q];
        s.x += v.x; s.y += v.y; s.z += v.z; s.w += v.w;
        sq.x += v.x * v.x; sq.y += v.y * v.y; sq.z += v.z * v.z; sq.w += v.w * v.w;
        const int db = (8 * q + ((r & 15) << 5)) & 511;
        *(uint2*)(ximg + (size_t)r * 512 + db) = make_uint2(bfpack(v.x, v.y), bfpack(v.z, v.w));
    }
    const size_t p = (size_t)(blockIdx.x * 4 + g) * 64 + q;
    ((float4*)(ws + WS_PARTSUM))[p] = s;
    ((float4*)(ws + WS_PARTSQ))[p]  = sq;
}

// ===== K1b: reduce 2048 partials -> 256 =====
__global__ __launch_bounds__(256) void k_bn_mid(float* __restrict__ ws) {
    const int d = threadIdx.x, j = blockIdx.x;
    float s = 0.f, q = 0.f;
#pragma unroll
    for (int i = 0; i < 8; ++i) {
        s += ws[WS_PARTSUM + (size_t)(j * 8 + i) * DDIM + d];
        q += ws[WS_PARTSQ  + (size_t)(j * 8 + i) * DDIM + d];
    }
    ws[WS_MIDSUM + (size_t)j * DDIM + d] = s;
    ws[WS_MIDSQ  + (size_t)j * DDIM + d] = q;
}

// ===== K2: finalize BN stats =====
__global__ __launch_bounds__(256) void k_bn_final(const float* __restrict__ rmean_in,
                                                  const float* __restrict__ rvar_in,
                                                  float* __restrict__ ws,
                                                  float* __restrict__ out) {
    const int d = threadIdx.x;
    float s = 0.f, sq = 0.f;
    for (int b = 0; b < 256; ++b) {
        s  += ws[WS_MIDSUM + (size_t)b * DDIM + d];
        sq += ws[WS_MIDSQ  + (size_t)b * DDIM + d];
    }
    const float mean = s / (float)NROWS;
    float var = sq / (float)NROWS - mean * mean;
    var = fmaxf(var, 0.f);
    const float rstd = 1.0f / sqrtf(var + EPSV);
    const float nrm  = (1.0f - MOMV) * rmean_in[d] + MOMV * mean;
    const float varu = var * ((float)NROWS / (float)(NROWS - 1));
    const float nrv  = (1.0f - MOMV) * rvar_in[d] + MOMV * varu;
    ws[WS_MEAN + d] = mean;
    ws[WS_RSTD + d] = rstd;
    ws[WS_NRMEAN + d] = nrm;
    ws[WS_NRVAR + d] = nrv;
    out[O_RMEAN + d] = nrm;
    out[O_RVAR + d] = nrv;
}

// ===== K3: e' rows + bf16 image + b_k (one wave per k, shfl reduce) =====
__global__ __launch_bounds__(256) void k_eprime(const float* __restrict__ emb,
                                                float* __restrict__ ws) {
    const int t = threadIdx.x, l = t & 63, w = t >> 6;
    const int k = blockIdx.x * 4 + w;
    const float4 em = ((const float4*)emb)[(size_t)k * 64 + l];
    const float4 rs = ((const float4*)(ws + WS_RSTD))[l];
    const float4 mn = ((const float4*)(ws + WS_MEAN))[l];
    float4 e;
    e.x = em.x * rs.x; e.y = em.y * rs.y; e.z = em.z * rs.z; e.w = em.w * rs.w;
    ((float4*)(ws + WS_EPROW))[(size_t)k * 64 + l] = e;
    char* img = (char*)(ws + WS_EIMG);
    const int db = (8 * l + ((k & 15) << 5)) & 511;
    *(uint2*)(img + (size_t)k * 512 + db) = make_uint2(bfpack(e.x, e.y), bfpack(e.z, e.w));
    float red = em.x * em.x + 2.f * mn.x * e.x + em.y * em.y + 2.f * mn.y * e.y
              + em.z * em.z + 2.f * mn.z * e.z + em.w * em.w + 2.f * mn.w * e.w;
    red += __shfl_xor(red, 32); red += __shfl_xor(red, 16); red += __shfl_xor(red, 8);
    red += __shfl_xor(red, 4);  red += __shfl_xor(red, 2);  red += __shfl_xor(red, 1);
    if (l == 0) ws[WS_BVEC + k] = red;
}

// ===== K4: single-pass MFMA GEMM, packed med3 top-2 =====
// 2048 blocks = 512 row-tiles x 4 col-quarters; 4 waves x 32 rows each.
// LDS: 2 x 16KB E-chunk dbuf; LB(256,5) -> 5 blocks/CU (160KB LDS).
__global__ __launch_bounds__(256, 5) void k_gemm_min(float* __restrict__ ws) {
    extern __shared__ char smem[];      // 2 x 16384
    const int t = threadIdx.x, lane = t & 63, w = t >> 6;
    const int l4 = lane & 15, kg = lane >> 4;
    const int tile = blockIdx.x >> 2;
    const int cq   = blockIdx.x & 3;
    const int rowbase = tile * 128 + w * 32;
    const char* ximg = (const char*)(ws + WS_XIMG);
    const char* eimg = (const char*)(ws + WS_EIMG) + (size_t)cq * 524288;  // 1024 cols
    const float* bvec = ws + WS_BVEC;

    // A fragments: rows rowbase + m*16 + l4, all 8 k-steps (rotated image)
    bf16x8 a[2][8];
#pragma unroll
    for (int m = 0; m < 2; ++m) {
        const char* rp = ximg + (size_t)(rowbase + m * 16 + l4) * 512;
#pragma unroll
        for (int ts = 0; ts < 8; ++ts) {
            const int byte = ((kg * 16 + ts * 64) + (l4 << 5)) & 511;
            a[m][ts] = *(const bf16x8*)(rp + byte);
        }
    }

    float b1f[2][4], b2f[2][4];
#pragma unroll
    for (int m = 0; m < 2; ++m)
#pragma unroll
        for (int r = 0; r < 4; ++r) { b1f[m][r] = FLT_MAX; b2f[m][r] = FLT_MAX; }

    // prologue: stage chunk 0 (16KB)
#pragma unroll
    for (int rr = 0; rr < 4; ++rr) {
        const int off = rr * 4096 + w * 1024;
        GLOAD_LDS16(eimg + off + lane * 16, smem + off);
    }
    __syncthreads();

#pragma unroll 2
    for (int ch = 0; ch < 32; ++ch) {
        const char* cur = smem + (ch & 1) * 16384;
        if (ch + 1 < 32) {
            const char* src = eimg + (size_t)(ch + 1) * 16384;
            char* nb = smem + ((ch + 1) & 1) * 16384;
#pragma unroll
            for (int rr = 0; rr < 4; ++rr) {
                const int off = rr * 4096 + w * 1024;
                GLOAD_LDS16(src + off + lane * 16, nb + off);
            }
        }

        f32x4 acc[2][2];
#pragma unroll
        for (int m = 0; m < 2; ++m)
#pragma unroll
            for (int n = 0; n < 2; ++n) acc[m][n] = 0.f;

#pragma unroll
        for (int ts = 0; ts < 8; ++ts) {
            const int rot = ((kg * 16 + ts * 64) + (l4 << 5)) & 511;
            bf16x8 bfr[2];
#pragma unroll
            for (int n = 0; n < 2; ++n)
                bfr[n] = *(const bf16x8*)(cur + (n * 16 + l4) * 512 + rot);
#pragma unroll
            for (int m = 0; m < 2; ++m)
#pragma unroll
                for (int n = 0; n < 2; ++n)
                    acc[m][n] = __builtin_amdgcn_mfma_f32_16x16x32_bf16(a[m][ts], bfr[n], acc[m][n], 0, 0, 0);
        }

#pragma unroll
        for (int n = 0; n < 2; ++n) {
            const unsigned col = (unsigned)(cq * 1024 + ch * 32 + n * 16 + l4);
            const float bc = bvec[col];
#pragma unroll
            for (int m = 0; m < 2; ++m)
#pragma unroll
                for (int r = 0; r < 4; ++r) {
                    const float s = fmaf(-2.f, acc[m][n][r], bc);
                    const float p = __uint_as_float(
                        (__float_as_uint(s) & 0xFFFFF000u) | col);   // v_and_or_b32
                    b2f[m][r] = __builtin_amdgcn_fmed3f(p, b1f[m][r], b2f[m][r]);
                    b1f[m][r] = fminf(p, b1f[m][r]);
                }
        }
        __syncthreads();   // drains prefetch + protects cur reuse
    }

    // merge top-2 across the 16 l4-lanes holding each row; write packed pair
    float2* rowinfo = (float2*)(ws + WS_ROWINFO);
#pragma unroll
    for (int m = 0; m < 2; ++m)
#pragma unroll
        for (int r = 0; r < 4; ++r) {
            float v1 = b1f[m][r], v2 = b2f[m][r];
#pragma unroll
            for (int st = 1; st < 16; st <<= 1) {
                const float o1 = __shfl_xor(v1, st);
                const float o2 = __shfl_xor(v2, st);
                const float mm = fminf(v2, o2);
                v2 = __builtin_amdgcn_fmed3f(v1, o1, mm);
                v1 = fminf(v1, o1);
            }
            if (l4 == 0) {
                const int row = rowbase + m * 16 + kg * 4 + r;
                rowinfo[(size_t)row * 4 + cq] = make_float2(v1, v2);
            }
        }
}

// ===== K5: merge 4 col-quarter partials, flag close rows, hist clear rows =====
__global__ __launch_bounds__(256) void k_flag(float* __restrict__ ws,
                                              float* __restrict__ out) {
    const int r = blockIdx.x * 256 + threadIdx.x;
    const float2* rowinfo = (const float2*)(ws + WS_ROWINFO);
    float2 q = rowinfo[(size_t)r * 4];
    float v1 = q.x, v2 = q.y;
#pragma unroll
    for (int c = 1; c < 4; ++c) {
        q = rowinfo[(size_t)r * 4 + c];
        const float mm = fminf(v2, q.y);
        v2 = __builtin_amdgcn_fmed3f(v1, q.x, mm);
        v1 = fminf(v1, q.x);
    }
    const float v1v = unpackval(v1);
    const int   i1  = (int)(__float_as_uint(v1) & 0xFFFu);
    ws[WS_ROWTHR + r] = v1v + DELTA;
    if (unpackval(v2) - v1v <= DELTA) {
        const int pos = atomicAdd((int*)(ws + WS_NFLAG), 1);
        ((int*)(ws + WS_FLAG))[pos] = r;
    } else {
        out[O_IDX + r] = (float)i1;
        ((int*)(ws + WS_IDX))[r] = i1;
        atomicAdd((int*)(ws + WS_HIST) + i1, 1);
    }
}

// ===== K6: candidate-append mini-GEMM over flagged rows, col-sliced x8 =====
__global__ __launch_bounds__(256) void k_cand(float* __restrict__ ws) {
    extern __shared__ char smem[];      // 2 x 16384
    const int t = threadIdx.x, lane = t & 63, w = t >> 6;
    const int l4 = lane & 15, kg = lane >> 4;
    const char* ximg = (const char*)(ws + WS_XIMG);
    const char* eimg0 = (const char*)(ws + WS_EIMG);
    const float* bvec = ws + WS_BVEC;
    const int* flag = (const int*)(ws + WS_FLAG);
    int* cnt = (int*)(ws + WS_CNT);
    int* cand = (int*)(ws + WS_CAND);
    const int nflag = *(const int*)(ws + WS_NFLAG);
    if (nflag == 0) return;
    const int ntiles = (nflag + 127) >> 7;
    const int nitems = ntiles * 8;

    for (int item = blockIdx.x; item < nitems; item += gridDim.x) {
        const int tile = item >> 3, slice = item & 7;
        const int base = tile * 128 + w * 32;
        const char* eimg = eimg0 + (size_t)slice * 262144;   // 512 cols per slice
        bf16x8 a[2][8];
        int frow[2][4];
        float thr[2][4];
#pragma unroll
        for (int m = 0; m < 2; ++m) {
            const int ia = base + m * 16 + l4;
            const int rowa = flag[ia < nflag ? ia : (nflag - 1)];
            const char* rp = ximg + (size_t)rowa * 512;
#pragma unroll
            for (int ts = 0; ts < 8; ++ts) {
                const int byte = ((kg * 16 + ts * 64) + ((rowa & 15) << 5)) & 511;
                a[m][ts] = *(const bf16x8*)(rp + byte);
            }
#pragma unroll
            for (int r = 0; r < 4; ++r) {
                const int ie = base + m * 16 + kg * 4 + r;
                const bool val = ie < nflag;
                const int rowe = flag[val ? ie : (nflag - 1)];
                frow[m][r] = rowe;
                thr[m][r] = val ? ws[WS_ROWTHR + rowe] : -FLT_MAX;
            }
        }
#pragma unroll
        for (int rr = 0; rr < 4; ++rr) {
            const int off = rr * 4096 + w * 1024;
            GLOAD_LDS16(eimg + off + lane * 16, smem + off);
        }
        __syncthreads();

        for (int ch = 0; ch < 16; ++ch) {
            const char* cur = smem + (ch & 1) * 16384;
            if (ch + 1 < 16) {
                const char* src = eimg + (size_t)(ch + 1) * 16384;
                char* nb = smem + ((ch + 1) & 1) * 16384;
#pragma unroll
                for (int rr = 0; rr < 4; ++rr) {
                    const int off = rr * 4096 + w * 1024;
                    GLOAD_LDS16(src + off + lane * 16, nb + off);
                }
            }
            f32x4 acc[2][2];
#pragma unroll
            for (int m = 0; m < 2; ++m)
#pragma unroll
                for (int n = 0; n < 2; ++n) acc[m][n] = 0.f;
#pragma unroll
            for (int ts = 0; ts < 8; ++ts) {
                const int rot = ((kg * 16 + ts * 64) + (l4 << 5)) & 511;
                bf16x8 bfr[2];
#pragma unroll
                for (int n = 0; n < 2; ++n)
                    bfr[n] = *(const bf16x8*)(cur + (n * 16 + l4) * 512 + rot);
#pragma unroll
                for (int m = 0; m < 2; ++m)
#pragma unroll
                    for (int n = 0; n < 2; ++n)
                        acc[m][n] = __builtin_amdgcn_mfma_f32_16x16x32_bf16(a[m][ts], bfr[n], acc[m][n], 0, 0, 0);
            }
#pragma unroll
            for (int n = 0; n < 2; ++n) {
                const int col = slice * 512 + ch * 32 + n * 16 + l4;
                const float bc = bvec[col];
#pragma unroll
                for (int m = 0; m < 2; ++m)
#pragma unroll
                    for (int r = 0; r < 4; ++r) {
                        const float s = fmaf(-2.f, acc[m][n][r], bc);
                        if (s <= thr[m][r]) {
                            const int rr2 = frow[m][r];
                            const int pos = atomicAdd(&cnt[rr2], 1);
                            if (pos < CAP) cand[(size_t)rr2 * CAP + pos] = col;
                        }
                    }
            }
            __syncthreads();
        }
    }
}

// ===== K7: exact fp32 resolve for flagged rows (+hist) =====
__global__ __launch_bounds__(256) void k_resolve_f(const float* __restrict__ x,
                                                   float* __restrict__ ws,
                                                   float* __restrict__ out) {
    const int t = threadIdx.x, lane = t & 63;
    const int gw = (blockIdx.x * 256 + t) >> 6;     // 1024 waves
    const int nflag = *(const int*)(ws + WS_NFLAG);
    const int* flag = (const int*)(ws + WS_FLAG);
    const int* cnt = (const int*)(ws + WS_CNT);
    const int* cand = (const int*)(ws + WS_CAND);
    const float* eprow = ws + WS_EPROW;
    const float* bvec = ws + WS_BVEC;
    int* idx_int = (int*)(ws + WS_IDX);
    for (int i = gw; i < nflag; i += 1024) {
        const int row = flag[i];
        const float4 xr = ((const float4*)(x + (size_t)row * DDIM))[lane];
        const int n = cnt[row];
        float bestv = FLT_MAX;
        int bestk = KDIM;
        if (n >= 1 && n <= CAP) {
            for (int c = 0; c < n; ++c) {
                const int k = cand[(size_t)row * CAP + c];
                const float4 er = ((const float4*)(eprow + (size_t)k * DDIM))[lane];
                float p = xr.x * er.x + xr.y * er.y + xr.z * er.z + xr.w * er.w;
                p += __shfl_xor(p, 32); p += __shfl_xor(p, 16); p += __shfl_xor(p, 8);
                p += __shfl_xor(p, 4);  p += __shfl_xor(p, 2);  p += __shfl_xor(p, 1);
                const float s = fmaf(-2.f, p, bvec[k]);
                if (s < bestv || (s == bestv && k < bestk)) { bestv = s; bestk = k; }
            }
        } else {   // overflow / safety fallback: exact full scan
            for (int k = 0; k < KDIM; ++k) {
                const float4 er = ((const float4*)(eprow + (size_t)k * DDIM))[lane];
                float p = xr.x * er.x + xr.y * er.y + xr.z * er.z + xr.w * er.w;
                p += __shfl_xor(p, 32); p += __shfl_xor(p, 16); p += __shfl_xor(p, 8);
                p += __shfl_xor(p, 4);  p += __shfl_xor(p, 2);  p += __shfl_xor(p, 1);
                const float s = fmaf(-2.f, p, bvec[k]);
                if (s < bestv || (s == bestv && k < bestk)) { bestv = s; bestk = k; }
            }
        }
        if (lane == 0) {
            out[O_IDX + row] = (float)bestk;
            idx_int[row] = bestk;
            atomicAdd((int*)(ws + WS_HIST) + bestk, 1);
        }
    }
}

// ===== K8: dual prefix sums + segment descriptors + EMA cluster size =====
__global__ __launch_bounds__(256) void k_scan(const float* __restrict__ cs_in,
                                              float* __restrict__ ws) {
    __shared__ int lsum[256], lseg[256];
    __shared__ float redf[256];
    const int t = threadIdx.x;
    const int* hist = (const int*)(ws + WS_HIST);
    int h[16];
    int s = 0, g = 0;
#pragma unroll
    for (int i = 0; i < 16; ++i) {
        h[i] = hist[t * 16 + i];
        s += h[i];
        g += (h[i] + SEG - 1) / SEG;
    }
    lsum[t] = s; lseg[t] = g;
    __syncthreads();
    int v = s, u = g;
    for (int off = 1; off < 256; off <<= 1) {
        const int av = (t >= off) ? lsum[t - off] : 0;
        const int au = (t >= off) ? lseg[t - off] : 0;
        __syncthreads();
        v += av; u += au;
        lsum[t] = v; lseg[t] = u;
        __syncthreads();
    }
    int runs = v - s, rung = u - g;
    int* start = (int*)(ws + WS_START);
    int* fillpos = (int*)(ws + WS_FILLPOS);
    int* segst = (int*)(ws + WS_SEGSTART);
    int* seglist = (int*)(ws + WS_SEGLIST);
    float emapart = 0.f;
#pragma unroll
    for (int i = 0; i < 16; ++i) {
        const int k = t * 16 + i;
        start[k] = runs;
        fillpos[k] = runs;
        segst[k] = rung;
        const int ns = (h[i] + SEG - 1) / SEG;
        for (int j = 0; j < ns; ++j) seglist[rung + j] = (k << 10) | j;
        runs += h[i];
        rung += ns;
        const float ncs = cs_in[k] * DECAYV + (1.0f - DECAYV) * (float)h[i];
        ws[WS_NCSRAW + k] = ncs;
        emapart += ncs;
    }
    if (t == 255) {
        segst[KDIM] = rung;
        *(int*)(ws + WS_NSEG) = rung;
    }
    redf[t] = emapart;
    __syncthreads();
    for (int ss = 128; ss > 0; ss >>= 1) { if (t < ss) redf[t] += redf[t + ss]; __syncthreads(); }
    if (t == 0) ws[WS_NTOT] = redf[0];
}

// ===== K8c: fill per-cluster row lists =====
__global__ __launch_bounds__(256) void k_fill(float* __restrict__ ws) {
    const int r = blockIdx.x * 256 + threadIdx.x;
    const int k = ((const int*)(ws + WS_IDX))[r];
    const int pos = atomicAdd((int*)(ws + WS_FILLPOS) + k, 1);
    ((int*)(ws + WS_ROWLIST))[pos] = r;
}

// ===== K8e: per-segment gather partial sums, float4 + 4-group combine =====
__global__ __launch_bounds__(256) void k_gather_seg(const float* __restrict__ x,
                                                    float* __restrict__ ws) {
    __shared__ float4 ls[4][64];
    const int b = blockIdx.x;
    if (b >= *(const int*)(ws + WS_NSEG)) return;
    const int e = ((const int*)(ws + WS_SEGLIST))[b];
    const int k = e >> 10, j = e & 1023;
    const int base = ((const int*)(ws + WS_START))[k];
    const int n = ((const int*)(ws + WS_HIST))[k];
    const int st = base + j * SEG;
    const int en = min(st + SEG, base + n);
    const int* rowlist = (const int*)(ws + WS_ROWLIST);
    const int t = threadIdx.x, q = t & 63, g = t >> 6;
    const float4* x4 = (const float4*)x;
    float4 s = make_float4(0.f, 0.f, 0.f, 0.f);
    for (int i = st + g; i < en; i += 4) {
        const float4 v = x4[(size_t)rowlist[i] * 64 + q];
        s.x += v.x; s.y += v.y; s.z += v.z; s.w += v.w;
    }
    ls[g][q] = s;
    __syncthreads();
    if (t < 64) {
        const float4 a0 = ls[0][t], a1 = ls[1][t], a2 = ls[2][t], a3 = ls[3][t];
        float4 r;
        r.x = (a0.x + a1.x) + (a2.x + a3.x);
        r.y = (a0.y + a1.y) + (a2.y + a3.y);
        r.z = (a0.z + a1.z) + (a2.z + a3.z);
        r.w = (a0.w + a1.w) + (a2.w + a3.w);
        ((float4*)(ws + WS_DWPART))[(size_t)b * 64 + t] = r;
    }
}

// ===== K9: streaming finalize [K,D] outputs (float4, one wave per k) =====
__global__ __launch_bounds__(64) void k_final(const float* __restrict__ ema_w,
                                              const float* __restrict__ ws,
                                              float* __restrict__ out) {
    const int k = blockIdx.x;   // 4096 blocks
    const int q = threadIdx.x;  // d-quad
    const int* segst = (const int*)(ws + WS_SEGSTART);
    const int ss = segst[k];
    const int ns = segst[k + 1] - ss;
    const float4* dwpart = (const float4*)(ws + WS_DWPART);
    float4 a = make_float4(0.f, 0.f, 0.f, 0.f);
    for (int j = 0; j < ns; ++j) {
        const float4 v = dwpart[(size_t)(ss + j) * 64 + q];
        a.x += v.x; a.y += v.y; a.z += v.z; a.w += v.w;
    }
    const int n = ((const int*)(ws + WS_HIST))[k];
    const float ntot = ws[WS_NTOT];
    const float ncs  = (ws[WS_NCSRAW + k] + 1e-5f) / (ntot + (float)KDIM * 1e-5f) * ntot;
    const float4 mn = ((const float4*)(ws + WS_MEAN))[q];
    const float4 rs = ((const float4*)(ws + WS_RSTD))[q];
    const float4 nrv = ((const float4*)(ws + WS_NRVAR))[q];
    const float4 nrm = ((const float4*)(ws + WS_NRMEAN))[q];
    const float4 ew = ((const float4*)ema_w)[(size_t)k * 64 + q];
    const float fn = (float)n;
    float4 nwv, nembv, eov;
    nwv.x = ew.x * DECAYV + (1.f - DECAYV) * ((a.x - fn * mn.x) * rs.x);
    nwv.y = ew.y * DECAYV + (1.f - DECAYV) * ((a.y - fn * mn.y) * rs.y);
    nwv.z = ew.z * DECAYV + (1.f - DECAYV) * ((a.z - fn * mn.z) * rs.z);
    nwv.w = ew.w * DECAYV + (1.f - DECAYV) * ((a.w - fn * mn.w) * rs.w);
    const float inv = 1.0f / ncs;
    nembv.x = nwv.x * inv; nembv.y = nwv.y * inv;
    nembv.z = nwv.z * inv; nembv.w = nwv.w * inv;
    eov.x = nembv.x * sqrtf(nrv.x + EPSV) + nrm.x;
    eov.y = nembv.y * sqrtf(nrv.y + EPSV) + nrm.y;
    eov.z = nembv.z * sqrtf(nrv.z + EPSV) + nrm.z;
    eov.w = nembv.w * sqrtf(nrv.w + EPSV) + nrm.w;
    ((float4*)(out + O_EMB))[(size_t)k * 64 + q]  = nembv;
    ((float4*)(out + O_EOUT))[(size_t)k * 64 + q] = eov;
    ((float4*)(out + O_EMAW))[(size_t)k * 64 + q] = nwv;
    if (q == 0) out[O_CS + k] = ncs;
}

// ===== launcher =====
extern "C" void kernel_launch(void* const* d_in, const int* in_sizes, int n_in,
                              void* d_out, int out_size, void* d_ws, size_t ws_size,
                              hipStream_t stream) {
    const float* x     = (const float*)d_in[0];
    const float* emb   = (const float*)d_in[1];
    const float* cs    = (const float*)d_in[2];
    const float* ema_w = (const float*)d_in[3];
    const float* rmean = (const float*)d_in[4];
    const float* rvar  = (const float*)d_in[5];
    float* out = (float*)d_out;
    float* ws  = (float*)d_ws;

    // zero cnt + nflag + hist (contiguous at ws base, ~280 KB)
    hipMemsetAsync(ws, 0, WS_ZEND * sizeof(float), stream);

    k_bnpack<<<512, 256, 0, stream>>>(x, ws);
    k_bn_mid<<<256, 256, 0, stream>>>(ws);
    k_bn_final<<<1, 256, 0, stream>>>(rmean, rvar, ws, out);
    k_eprime<<<KDIM / 4, 256, 0, stream>>>(emb, ws);

    constexpr int LDSB = 32768;
    k_gemm_min<<<2048, 256, LDSB, stream>>>(ws);
    k_flag<<<NROWS / 256, 256, 0, stream>>>(ws, out);
    k_cand<<<512, 256, LDSB, stream>>>(ws);
    k_resolve_f<<<256, 256, 0, stream>>>(x, ws, out);

    k_scan<<<1, 256, 0, stream>>>(cs, ws);
    k_fill<<<NROWS / 256, 256, 0, stream>>>(ws);
    k_gather_seg<<<4608, 256, 0, stream>>>(x, ws);
    k_final<<<KDIM, 64, 0, stream>>>(ema_w, ws, out);
}

// Round 9
// 327.995 us; speedup vs baseline: 2.0528x; 2.0528x over previous
//
#include <hip/hip_runtime.h>
#include <cfloat>
#include <cmath>

#define NROWS 65536
#define DDIM 256
#define KDIM 4096

typedef short bf16x8 __attribute__((ext_vector_type(8)));
typedef float f32x4 __attribute__((ext_vector_type(4)));

constexpr float EPSV = 1e-5f;
constexpr float DECAYV = 0.99f;
constexpr float MOMV = 0.1f;
constexpr float DELTA = 1.0f;   // bf16 noise (~0.4) + pack trunc (0.25) + slack
constexpr int CAP = 16;
constexpr int SEG = 128;        // rows per gather segment

// ---------------- workspace layout (float offsets) ----------------
constexpr size_t WS_CNT     = 0;                               // int[N] cand counts (zeroed)
constexpr size_t WS_NFLAG   = WS_CNT + NROWS;                  // int[1]+pad (zeroed)
constexpr size_t WS_HIST    = WS_NFLAG + 64;                   // int[K] (zeroed)
constexpr size_t WS_ZEND    = WS_HIST + KDIM;                  // end of zeroed region
constexpr size_t WS_START   = WS_ZEND;                         // int[K]
constexpr size_t WS_FILLPOS = WS_START + KDIM;                 // int[K]
constexpr size_t WS_SEGSTART= WS_FILLPOS + KDIM;               // int[K+64]
constexpr size_t WS_NSEG    = WS_SEGSTART + KDIM + 64;         // int[1]+pad
constexpr size_t WS_SEGLIST = WS_NSEG + 64;                    // int[4608+pad]
constexpr size_t WS_PARTSUM = WS_SEGLIST + 4672;               // [2048][256]
constexpr size_t WS_PARTSQ  = WS_PARTSUM + 2048 * DDIM;        // [2048][256]
constexpr size_t WS_MIDSUM  = WS_PARTSQ + 2048 * DDIM;         // [256][256]
constexpr size_t WS_MIDSQ   = WS_MIDSUM + 256 * DDIM;          // [256][256]
constexpr size_t WS_MEAN    = WS_MIDSQ + 256 * DDIM;           // [256]
constexpr size_t WS_RSTD    = WS_MEAN + DDIM;                  // [256]
constexpr size_t WS_NRMEAN  = WS_RSTD + DDIM;                  // [256]
constexpr size_t WS_NRVAR   = WS_NRMEAN + DDIM;                // [256]
constexpr size_t WS_BVEC    = WS_NRVAR + DDIM;                 // [4096]
constexpr size_t WS_NCSRAW  = WS_BVEC + KDIM;                  // [4096]
constexpr size_t WS_NTOT    = WS_NCSRAW + KDIM;                // [1]+pad
constexpr size_t WS_ROWINFO = WS_NTOT + 64;                    // float2[N][4] packed (v1,v2)
constexpr size_t WS_IDX     = WS_ROWINFO + 8 * (size_t)NROWS;  // int[N]
constexpr size_t WS_ROWTHR  = WS_IDX + NROWS;                  // float[N]
constexpr size_t WS_FLAG    = WS_ROWTHR + NROWS;               // int[N]
constexpr size_t WS_ROWLIST = WS_FLAG + NROWS;                 // int[N]
constexpr size_t WS_CAND    = WS_ROWLIST + NROWS;              // int[N*CAP]
constexpr size_t WS_DWPART  = WS_CAND;                         // ALIAS: float[4608][256] over CAND+EPROW (dead by then)
constexpr size_t WS_EPROW   = WS_CAND + (size_t)NROWS * CAP;   // float[K][D]
constexpr size_t WS_EIMG    = WS_EPROW + (size_t)KDIM * DDIM;  // bf16 E image 2MB
constexpr size_t WS_XIMG    = WS_EIMG + 524288;                // bf16 X image 32MB

// ---------------- output layout (float offsets) ----------------
constexpr size_t O_IDX   = 0;
constexpr size_t O_EMB   = NROWS;
constexpr size_t O_EOUT  = O_EMB + (size_t)KDIM * DDIM;
constexpr size_t O_CS    = O_EOUT + (size_t)KDIM * DDIM;
constexpr size_t O_EMAW  = O_CS + KDIM;
constexpr size_t O_RMEAN = O_EMAW + (size_t)KDIM * DDIM;
constexpr size_t O_RVAR  = O_RMEAN + DDIM;

__device__ inline unsigned bfpack(float a, float b) {   // RNE f32->bf16 pair
    unsigned ua = __float_as_uint(a), ub = __float_as_uint(b);
    ua = (ua + 0x7FFFu + ((ua >> 16) & 1u)) >> 16;
    ub = (ub + 0x7FFFu + ((ub >> 16) & 1u)) & 0xFFFF0000u;
    return (ua & 0xFFFFu) | ub;
}

__device__ inline float unpackval(float p) {            // strip idx bits -> value
    return __uint_as_float(__float_as_uint(p) & 0xFFFFF000u);
}

#define GLOAD_LDS16(g, l) __builtin_amdgcn_global_load_lds(                       \
        (const __attribute__((address_space(1))) void*)(g),                        \
        (__attribute__((address_space(3))) void*)(l), 16, 0, 0)

// ===== K1: BN partial sums + fused x -> bf16 rotated image (float4) =====
// 512 blocks x 256 thr: 4 row-groups x 64 d-quads, 32 rows per group.
__global__ __launch_bounds__(256) void k_bnpack(const float* __restrict__ x,
                                                float* __restrict__ ws) {
    const int t = threadIdx.x;
    const int q = t & 63, g = t >> 6;
    const int r0 = blockIdx.x * 128 + g * 32;
    char* ximg = (char*)(ws + WS_XIMG);
    const float4* x4 = (const float4*)x;
    float4 s = make_float4(0.f, 0.f, 0.f, 0.f);
    float4 sq = make_float4(0.f, 0.f, 0.f, 0.f);
#pragma unroll 4
    for (int i = 0; i < 32; ++i) {
        const int r = r0 + i;
        const float4 v = x4[(size_t)r * 64 + q];
        s.x += v.x; s.y += v.y; s.z += v.z; s.w += v.w;
        sq.x += v.x * v.x; sq.y += v.y * v.y; sq.z += v.z * v.z; sq.w += v.w * v.w;
        const int db = (8 * q + ((r & 15) << 5)) & 511;
        *(uint2*)(ximg + (size_t)r * 512 + db) = make_uint2(bfpack(v.x, v.y), bfpack(v.z, v.w));
    }
    const size_t p = (size_t)(blockIdx.x * 4 + g) * 64 + q;
    ((float4*)(ws + WS_PARTSUM))[p] = s;
    ((float4*)(ws + WS_PARTSQ))[p]  = sq;
}

// ===== K1b: reduce 2048 partials -> 256 =====
__global__ __launch_bounds__(256) void k_bn_mid(float* __restrict__ ws) {
    const int d = threadIdx.x, j = blockIdx.x;
    float s = 0.f, q = 0.f;
#pragma unroll
    for (int i = 0; i < 8; ++i) {
        s += ws[WS_PARTSUM + (size_t)(j * 8 + i) * DDIM + d];
        q += ws[WS_PARTSQ  + (size_t)(j * 8 + i) * DDIM + d];
    }
    ws[WS_MIDSUM + (size_t)j * DDIM + d] = s;
    ws[WS_MIDSQ  + (size_t)j * DDIM + d] = q;
}

// ===== K2: finalize BN stats =====
__global__ __launch_bounds__(256) void k_bn_final(const float* __restrict__ rmean_in,
                                                  const float* __restrict__ rvar_in,
                                                  float* __restrict__ ws,
                                                  float* __restrict__ out) {
    const int d = threadIdx.x;
    float s = 0.f, sq = 0.f;
    for (int b = 0; b < 256; ++b) {
        s  += ws[WS_MIDSUM + (size_t)b * DDIM + d];
        sq += ws[WS_MIDSQ  + (size_t)b * DDIM + d];
    }
    const float mean = s / (float)NROWS;
    float var = sq / (float)NROWS - mean * mean;
    var = fmaxf(var, 0.f);
    const float rstd = 1.0f / sqrtf(var + EPSV);
    const float nrm  = (1.0f - MOMV) * rmean_in[d] + MOMV * mean;
    const float varu = var * ((float)NROWS / (float)(NROWS - 1));
    const float nrv  = (1.0f - MOMV) * rvar_in[d] + MOMV * varu;
    ws[WS_MEAN + d] = mean;
    ws[WS_RSTD + d] = rstd;
    ws[WS_NRMEAN + d] = nrm;
    ws[WS_NRVAR + d] = nrv;
    out[O_RMEAN + d] = nrm;
    out[O_RVAR + d] = nrv;
}

// ===== K3: e' rows + bf16 image + b_k (one wave per k, shfl reduce) =====
__global__ __launch_bounds__(256) void k_eprime(const float* __restrict__ emb,
                                                float* __restrict__ ws) {
    const int t = threadIdx.x, l = t & 63, w = t >> 6;
    const int k = blockIdx.x * 4 + w;
    const float4 em = ((const float4*)emb)[(size_t)k * 64 + l];
    const float4 rs = ((const float4*)(ws + WS_RSTD))[l];
    const float4 mn = ((const float4*)(ws + WS_MEAN))[l];
    float4 e;
    e.x = em.x * rs.x; e.y = em.y * rs.y; e.z = em.z * rs.z; e.w = em.w * rs.w;
    ((float4*)(ws + WS_EPROW))[(size_t)k * 64 + l] = e;
    char* img = (char*)(ws + WS_EIMG);
    const int db = (8 * l + ((k & 15) << 5)) & 511;
    *(uint2*)(img + (size_t)k * 512 + db) = make_uint2(bfpack(e.x, e.y), bfpack(e.z, e.w));
    float red = em.x * em.x + 2.f * mn.x * e.x + em.y * em.y + 2.f * mn.y * e.y
              + em.z * em.z + 2.f * mn.z * e.z + em.w * em.w + 2.f * mn.w * e.w;
    red += __shfl_xor(red, 32); red += __shfl_xor(red, 16); red += __shfl_xor(red, 8);
    red += __shfl_xor(red, 4);  red += __shfl_xor(red, 2);  red += __shfl_xor(red, 1);
    if (l == 0) ws[WS_BVEC + k] = red;
}

// ===== K4: single-pass MFMA GEMM, packed med3 top-2 =====
// 2048 blocks = 512 row-tiles x 4 col-quarters; 4 waves x 32 rows each.
// LDS: 2 x 16KB E-chunk dbuf. LB(256,4): VGPR=64 (a[2][8] fits in regs;
// LB(256,5) forced VGPR=48 -> A-frag spill -> 1.6GB scratch traffic, 3.4x slower).
__global__ __launch_bounds__(256, 4) void k_gemm_min(float* __restrict__ ws) {
    extern __shared__ char smem[];      // 2 x 16384
    const int t = threadIdx.x, lane = t & 63, w = t >> 6;
    const int l4 = lane & 15, kg = lane >> 4;
    const int tile = blockIdx.x >> 2;
    const int cq   = blockIdx.x & 3;
    const int rowbase = tile * 128 + w * 32;
    const char* ximg = (const char*)(ws + WS_XIMG);
    const char* eimg = (const char*)(ws + WS_EIMG) + (size_t)cq * 524288;  // 1024 cols
    const float* bvec = ws + WS_BVEC;

    // A fragments: rows rowbase + m*16 + l4, all 8 k-steps (rotated image)
    bf16x8 a[2][8];
#pragma unroll
    for (int m = 0; m < 2; ++m) {
        const char* rp = ximg + (size_t)(rowbase + m * 16 + l4) * 512;
#pragma unroll
        for (int ts = 0; ts < 8; ++ts) {
            const int byte = ((kg * 16 + ts * 64) + (l4 << 5)) & 511;
            a[m][ts] = *(const bf16x8*)(rp + byte);
        }
    }

    float b1f[2][4], b2f[2][4];
#pragma unroll
    for (int m = 0; m < 2; ++m)
#pragma unroll
        for (int r = 0; r < 4; ++r) { b1f[m][r] = FLT_MAX; b2f[m][r] = FLT_MAX; }

    // prologue: stage chunk 0 (16KB)
#pragma unroll
    for (int rr = 0; rr < 4; ++rr) {
        const int off = rr * 4096 + w * 1024;
        GLOAD_LDS16(eimg + off + lane * 16, smem + off);
    }
    __syncthreads();

    for (int ch = 0; ch < 32; ++ch) {
        const char* cur = smem + (ch & 1) * 16384;
        if (ch + 1 < 32) {
            const char* src = eimg + (size_t)(ch + 1) * 16384;
            char* nb = smem + ((ch + 1) & 1) * 16384;
#pragma unroll
            for (int rr = 0; rr < 4; ++rr) {
                const int off = rr * 4096 + w * 1024;
                GLOAD_LDS16(src + off + lane * 16, nb + off);
            }
        }

        f32x4 acc[2][2];
#pragma unroll
        for (int m = 0; m < 2; ++m)
#pragma unroll
            for (int n = 0; n < 2; ++n) acc[m][n] = 0.f;

#pragma unroll
        for (int ts = 0; ts < 8; ++ts) {
            const int rot = ((kg * 16 + ts * 64) + (l4 << 5)) & 511;
            bf16x8 bfr[2];
#pragma unroll
            for (int n = 0; n < 2; ++n)
                bfr[n] = *(const bf16x8*)(cur + (n * 16 + l4) * 512 + rot);
#pragma unroll
            for (int m = 0; m < 2; ++m)
#pragma unroll
                for (int n = 0; n < 2; ++n)
                    acc[m][n] = __builtin_amdgcn_mfma_f32_16x16x32_bf16(a[m][ts], bfr[n], acc[m][n], 0, 0, 0);
        }

#pragma unroll
        for (int n = 0; n < 2; ++n) {
            const unsigned col = (unsigned)(cq * 1024 + ch * 32 + n * 16 + l4);
            const float bc = bvec[col];
#pragma unroll
            for (int m = 0; m < 2; ++m)
#pragma unroll
                for (int r = 0; r < 4; ++r) {
                    const float s = fmaf(-2.f, acc[m][n][r], bc);
                    const float p = __uint_as_float(
                        (__float_as_uint(s) & 0xFFFFF000u) | col);   // v_and_or_b32
                    b2f[m][r] = __builtin_amdgcn_fmed3f(p, b1f[m][r], b2f[m][r]);
                    b1f[m][r] = fminf(p, b1f[m][r]);
                }
        }
        __syncthreads();   // drains prefetch + protects cur reuse
    }

    // merge top-2 across the 16 l4-lanes holding each row; write packed pair
    float2* rowinfo = (float2*)(ws + WS_ROWINFO);
#pragma unroll
    for (int m = 0; m < 2; ++m)
#pragma unroll
        for (int r = 0; r < 4; ++r) {
            float v1 = b1f[m][r], v2 = b2f[m][r];
#pragma unroll
            for (int st = 1; st < 16; st <<= 1) {
                const float o1 = __shfl_xor(v1, st);
                const float o2 = __shfl_xor(v2, st);
                const float mm = fminf(v2, o2);
                v2 = __builtin_amdgcn_fmed3f(v1, o1, mm);
                v1 = fminf(v1, o1);
            }
            if (l4 == 0) {
                const int row = rowbase + m * 16 + kg * 4 + r;
                rowinfo[(size_t)row * 4 + cq] = make_float2(v1, v2);
            }
        }
}

// ===== K5: merge 4 col-quarter partials, flag close rows, hist clear rows =====
__global__ __launch_bounds__(256) void k_flag(float* __restrict__ ws,
                                              float* __restrict__ out) {
    const int r = blockIdx.x * 256 + threadIdx.x;
    const float2* rowinfo = (const float2*)(ws + WS_ROWINFO);
    float2 q = rowinfo[(size_t)r * 4];
    float v1 = q.x, v2 = q.y;
#pragma unroll
    for (int c = 1; c < 4; ++c) {
        q = rowinfo[(size_t)r * 4 + c];
        const float mm = fminf(v2, q.y);
        v2 = __builtin_amdgcn_fmed3f(v1, q.x, mm);
        v1 = fminf(v1, q.x);
    }
    const float v1v = unpackval(v1);
    const int   i1  = (int)(__float_as_uint(v1) & 0xFFFu);
    ws[WS_ROWTHR + r] = v1v + DELTA;
    if (unpackval(v2) - v1v <= DELTA) {
        const int pos = atomicAdd((int*)(ws + WS_NFLAG), 1);
        ((int*)(ws + WS_FLAG))[pos] = r;
    } else {
        out[O_IDX + r] = (float)i1;
        ((int*)(ws + WS_IDX))[r] = i1;
        atomicAdd((int*)(ws + WS_HIST) + i1, 1);
    }
}

// ===== K6: candidate-append mini-GEMM over flagged rows, col-sliced x8 =====
__global__ __launch_bounds__(256) void k_cand(float* __restrict__ ws) {
    extern __shared__ char smem[];      // 2 x 16384
    const int t = threadIdx.x, lane = t & 63, w = t >> 6;
    const int l4 = lane & 15, kg = lane >> 4;
    const char* ximg = (const char*)(ws + WS_XIMG);
    const char* eimg0 = (const char*)(ws + WS_EIMG);
    const float* bvec = ws + WS_BVEC;
    const int* flag = (const int*)(ws + WS_FLAG);
    int* cnt = (int*)(ws + WS_CNT);
    int* cand = (int*)(ws + WS_CAND);
    const int nflag = *(const int*)(ws + WS_NFLAG);
    if (nflag == 0) return;
    const int ntiles = (nflag + 127) >> 7;
    const int nitems = ntiles * 8;

    for (int item = blockIdx.x; item < nitems; item += gridDim.x) {
        const int tile = item >> 3, slice = item & 7;
        const int base = tile * 128 + w * 32;
        const char* eimg = eimg0 + (size_t)slice * 262144;   // 512 cols per slice
        bf16x8 a[2][8];
        int frow[2][4];
        float thr[2][4];
#pragma unroll
        for (int m = 0; m < 2; ++m) {
            const int ia = base + m * 16 + l4;
            const int rowa = flag[ia < nflag ? ia : (nflag - 1)];
            const char* rp = ximg + (size_t)rowa * 512;
#pragma unroll
            for (int ts = 0; ts < 8; ++ts) {
                const int byte = ((kg * 16 + ts * 64) + ((rowa & 15) << 5)) & 511;
                a[m][ts] = *(const bf16x8*)(rp + byte);
            }
#pragma unroll
            for (int r = 0; r < 4; ++r) {
                const int ie = base + m * 16 + kg * 4 + r;
                const bool val = ie < nflag;
                const int rowe = flag[val ? ie : (nflag - 1)];
                frow[m][r] = rowe;
                thr[m][r] = val ? ws[WS_ROWTHR + rowe] : -FLT_MAX;
            }
        }
#pragma unroll
        for (int rr = 0; rr < 4; ++rr) {
            const int off = rr * 4096 + w * 1024;
            GLOAD_LDS16(eimg + off + lane * 16, smem + off);
        }
        __syncthreads();

        for (int ch = 0; ch < 16; ++ch) {
            const char* cur = smem + (ch & 1) * 16384;
            if (ch + 1 < 16) {
                const char* src = eimg + (size_t)(ch + 1) * 16384;
                char* nb = smem + ((ch + 1) & 1) * 16384;
#pragma unroll
                for (int rr = 0; rr < 4; ++rr) {
                    const int off = rr * 4096 + w * 1024;
                    GLOAD_LDS16(src + off + lane * 16, nb + off);
                }
            }
            f32x4 acc[2][2];
#pragma unroll
            for (int m = 0; m < 2; ++m)
#pragma unroll
                for (int n = 0; n < 2; ++n) acc[m][n] = 0.f;
#pragma unroll
            for (int ts = 0; ts < 8; ++ts) {
                const int rot = ((kg * 16 + ts * 64) + (l4 << 5)) & 511;
                bf16x8 bfr[2];
#pragma unroll
                for (int n = 0; n < 2; ++n)
                    bfr[n] = *(const bf16x8*)(cur + (n * 16 + l4) * 512 + rot);
#pragma unroll
                for (int m = 0; m < 2; ++m)
#pragma unroll
                    for (int n = 0; n < 2; ++n)
                        acc[m][n] = __builtin_amdgcn_mfma_f32_16x16x32_bf16(a[m][ts], bfr[n], acc[m][n], 0, 0, 0);
            }
#pragma unroll
            for (int n = 0; n < 2; ++n) {
                const int col = slice * 512 + ch * 32 + n * 16 + l4;
                const float bc = bvec[col];
#pragma unroll
                for (int m = 0; m < 2; ++m)
#pragma unroll
                    for (int r = 0; r < 4; ++r) {
                        const float s = fmaf(-2.f, acc[m][n][r], bc);
                        if (s <= thr[m][r]) {
                            const int rr2 = frow[m][r];
                            const int pos = atomicAdd(&cnt[rr2], 1);
                            if (pos < CAP) cand[(size_t)rr2 * CAP + pos] = col;
                        }
                    }
            }
            __syncthreads();
        }
    }
}

// ===== K7: exact fp32 resolve for flagged rows (+hist) =====
__global__ __launch_bounds__(256) void k_resolve_f(const float* __restrict__ x,
                                                   float* __restrict__ ws,
                                                   float* __restrict__ out) {
    const int t = threadIdx.x, lane = t & 63;
    const int gw = (blockIdx.x * 256 + t) >> 6;     // 1024 waves
    const int nflag = *(const int*)(ws + WS_NFLAG);
    const int* flag = (const int*)(ws + WS_FLAG);
    const int* cnt = (const int*)(ws + WS_CNT);
    const int* cand = (const int*)(ws + WS_CAND);
    const float* eprow = ws + WS_EPROW;
    const float* bvec = ws + WS_BVEC;
    int* idx_int = (int*)(ws + WS_IDX);
    for (int i = gw; i < nflag; i += 1024) {
        const int row = flag[i];
        const float4 xr = ((const float4*)(x + (size_t)row * DDIM))[lane];
        const int n = cnt[row];
        float bestv = FLT_MAX;
        int bestk = KDIM;
        if (n >= 1 && n <= CAP) {
            for (int c = 0; c < n; ++c) {
                const int k = cand[(size_t)row * CAP + c];
                const float4 er = ((const float4*)(eprow + (size_t)k * DDIM))[lane];
                float p = xr.x * er.x + xr.y * er.y + xr.z * er.z + xr.w * er.w;
                p += __shfl_xor(p, 32); p += __shfl_xor(p, 16); p += __shfl_xor(p, 8);
                p += __shfl_xor(p, 4);  p += __shfl_xor(p, 2);  p += __shfl_xor(p, 1);
                const float s = fmaf(-2.f, p, bvec[k]);
                if (s < bestv || (s == bestv && k < bestk)) { bestv = s; bestk = k; }
            }
        } else {   // overflow / safety fallback: exact full scan
            for (int k = 0; k < KDIM; ++k) {
                const float4 er = ((const float4*)(eprow + (size_t)k * DDIM))[lane];
                float p = xr.x * er.x + xr.y * er.y + xr.z * er.z + xr.w * er.w;
                p += __shfl_xor(p, 32); p += __shfl_xor(p, 16); p += __shfl_xor(p, 8);
                p += __shfl_xor(p, 4);  p += __shfl_xor(p, 2);  p += __shfl_xor(p, 1);
                const float s = fmaf(-2.f, p, bvec[k]);
                if (s < bestv || (s == bestv && k < bestk)) { bestv = s; bestk = k; }
            }
        }
        if (lane == 0) {
            out[O_IDX + row] = (float)bestk;
            idx_int[row] = bestk;
            atomicAdd((int*)(ws + WS_HIST) + bestk, 1);
        }
    }
}

// ===== K8: dual prefix sums + segment descriptors + EMA cluster size =====
__global__ __launch_bounds__(256) void k_scan(const float* __restrict__ cs_in,
                                              float* __restrict__ ws) {
    __shared__ int lsum[256], lseg[256];
    __shared__ float redf[256];
    const int t = threadIdx.x;
    const int* hist = (const int*)(ws + WS_HIST);
    int h[16];
    int s = 0, g = 0;
#pragma unroll
    for (int i = 0; i < 16; ++i) {
        h[i] = hist[t * 16 + i];
        s += h[i];
        g += (h[i] + SEG - 1) / SEG;
    }
    lsum[t] = s; lseg[t] = g;
    __syncthreads();
    int v = s, u = g;
    for (int off = 1; off < 256; off <<= 1) {
        const int av = (t >= off) ? lsum[t - off] : 0;
        const int au = (t >= off) ? lseg[t - off] : 0;
        __syncthreads();
        v += av; u += au;
        lsum[t] = v; lseg[t] = u;
        __syncthreads();
    }
    int runs = v - s, rung = u - g;
    int* start = (int*)(ws + WS_START);
    int* fillpos = (int*)(ws + WS_FILLPOS);
    int* segst = (int*)(ws + WS_SEGSTART);
    int* seglist = (int*)(ws + WS_SEGLIST);
    float emapart = 0.f;
#pragma unroll
    for (int i = 0; i < 16; ++i) {
        const int k = t * 16 + i;
        start[k] = runs;
        fillpos[k] = runs;
        segst[k] = rung;
        const int ns = (h[i] + SEG - 1) / SEG;
        for (int j = 0; j < ns; ++j) seglist[rung + j] = (k << 10) | j;
        runs += h[i];
        rung += ns;
        const float ncs = cs_in[k] * DECAYV + (1.0f - DECAYV) * (float)h[i];
        ws[WS_NCSRAW + k] = ncs;
        emapart += ncs;
    }
    if (t == 255) {
        segst[KDIM] = rung;
        *(int*)(ws + WS_NSEG) = rung;
    }
    redf[t] = emapart;
    __syncthreads();
    for (int ss = 128; ss > 0; ss >>= 1) { if (t < ss) redf[t] += redf[t + ss]; __syncthreads(); }
    if (t == 0) ws[WS_NTOT] = redf[0];
}

// ===== K8c: fill per-cluster row lists =====
__global__ __launch_bounds__(256) void k_fill(float* __restrict__ ws) {
    const int r = blockIdx.x * 256 + threadIdx.x;
    const int k = ((const int*)(ws + WS_IDX))[r];
    const int pos = atomicAdd((int*)(ws + WS_FILLPOS) + k, 1);
    ((int*)(ws + WS_ROWLIST))[pos] = r;
}

// ===== K8e: per-segment gather partial sums, float4 + 4-group combine =====
__global__ __launch_bounds__(256) void k_gather_seg(const float* __restrict__ x,
                                                    float* __restrict__ ws) {
    __shared__ float4 ls[4][64];
    const int b = blockIdx.x;
    if (b >= *(const int*)(ws + WS_NSEG)) return;
    const int e = ((const int*)(ws + WS_SEGLIST))[b];
    const int k = e >> 10, j = e & 1023;
    const int base = ((const int*)(ws + WS_START))[k];
    const int n = ((const int*)(ws + WS_HIST))[k];
    const int st = base + j * SEG;
    const int en = min(st + SEG, base + n);
    const int* rowlist = (const int*)(ws + WS_ROWLIST);
    const int t = threadIdx.x, q = t & 63, g = t >> 6;
    const float4* x4 = (const float4*)x;
    float4 s = make_float4(0.f, 0.f, 0.f, 0.f);
    for (int i = st + g; i < en; i += 4) {
        const float4 v = x4[(size_t)rowlist[i] * 64 + q];
        s.x += v.x; s.y += v.y; s.z += v.z; s.w += v.w;
    }
    ls[g][q] = s;
    __syncthreads();
    if (t < 64) {
        const float4 a0 = ls[0][t], a1 = ls[1][t], a2 = ls[2][t], a3 = ls[3][t];
        float4 r;
        r.x = (a0.x + a1.x) + (a2.x + a3.x);
        r.y = (a0.y + a1.y) + (a2.y + a3.y);
        r.z = (a0.z + a1.z) + (a2.z + a3.z);
        r.w = (a0.w + a1.w) + (a2.w + a3.w);
        ((float4*)(ws + WS_DWPART))[(size_t)b * 64 + t] = r;
    }
}

// ===== K9: streaming finalize [K,D] outputs (float4, one wave per k) =====
__global__ __launch_bounds__(64) void k_final(const float* __restrict__ ema_w,
                                              const float* __restrict__ ws,
                                              float* __restrict__ out) {
    const int k = blockIdx.x;   // 4096 blocks
    const int q = threadIdx.x;  // d-quad
    const int* segst = (const int*)(ws + WS_SEGSTART);
    const int ss = segst[k];
    const int ns = segst[k + 1] - ss;
    const float4* dwpart = (const float4*)(ws + WS_DWPART);
    float4 a = make_float4(0.f, 0.f, 0.f, 0.f);
    for (int j = 0; j < ns; ++j) {
        const float4 v = dwpart[(size_t)(ss + j) * 64 + q];
        a.x += v.x; a.y += v.y; a.z += v.z; a.w += v.w;
    }
    const int n = ((const int*)(ws + WS_HIST))[k];
    const float ntot = ws[WS_NTOT];
    const float ncs  = (ws[WS_NCSRAW + k] + 1e-5f) / (ntot + (float)KDIM * 1e-5f) * ntot;
    const float4 mn = ((const float4*)(ws + WS_MEAN))[q];
    const float4 rs = ((const float4*)(ws + WS_RSTD))[q];
    const float4 nrv = ((const float4*)(ws + WS_NRVAR))[q];
    const float4 nrm = ((const float4*)(ws + WS_NRMEAN))[q];
    const float4 ew = ((const float4*)ema_w)[(size_t)k * 64 + q];
    const float fn = (float)n;
    float4 nwv, nembv, eov;
    nwv.x = ew.x * DECAYV + (1.f - DECAYV) * ((a.x - fn * mn.x) * rs.x);
    nwv.y = ew.y * DECAYV + (1.f - DECAYV) * ((a.y - fn * mn.y) * rs.y);
    nwv.z = ew.z * DECAYV + (1.f - DECAYV) * ((a.z - fn * mn.z) * rs.z);
    nwv.w = ew.w * DECAYV + (1.f - DECAYV) * ((a.w - fn * mn.w) * rs.w);
    const float inv = 1.0f / ncs;
    nembv.x = nwv.x * inv; nembv.y = nwv.y * inv;
    nembv.z = nwv.z * inv; nembv.w = nwv.w * inv;
    eov.x = nembv.x * sqrtf(nrv.x + EPSV) + nrm.x;
    eov.y = nembv.y * sqrtf(nrv.y + EPSV) + nrm.y;
    eov.z = nembv.z * sqrtf(nrv.z + EPSV) + nrm.z;
    eov.w = nembv.w * sqrtf(nrv.w + EPSV) + nrm.w;
    ((float4*)(out + O_EMB))[(size_t)k * 64 + q]  = nembv;
    ((float4*)(out + O_EOUT))[(size_t)k * 64 + q] = eov;
    ((float4*)(out + O_EMAW))[(size_t)k * 64 + q] = nwv;
    if (q == 0) out[O_CS + k] = ncs;
}

// ===== launcher =====
extern "C" void kernel_launch(void* const* d_in, const int* in_sizes, int n_in,
                              void* d_out, int out_size, void* d_ws, size_t ws_size,
                              hipStream_t stream) {
    const float* x     = (const float*)d_in[0];
    const float* emb   = (const float*)d_in[1];
    const float* cs    = (const float*)d_in[2];
    const float* ema_w = (const float*)d_in[3];
    const float* rmean = (const float*)d_in[4];
    const float* rvar  = (const float*)d_in[5];
    float* out = (float*)d_out;
    float* ws  = (float*)d_ws;

    // zero cnt + nflag + hist (contiguous at ws base, ~280 KB)
    hipMemsetAsync(ws, 0, WS_ZEND * sizeof(float), stream);

    k_bnpack<<<512, 256, 0, stream>>>(x, ws);
    k_bn_mid<<<256, 256, 0, stream>>>(ws);
    k_bn_final<<<1, 256, 0, stream>>>(rmean, rvar, ws, out);
    k_eprime<<<KDIM / 4, 256, 0, stream>>>(emb, ws);

    constexpr int LDSB = 32768;
    k_gemm_min<<<2048, 256, LDSB, stream>>>(ws);
    k_flag<<<NROWS / 256, 256, 0, stream>>>(ws, out);
    k_cand<<<512, 256, LDSB, stream>>>(ws);
    k_resolve_f<<<256, 256, 0, stream>>>(x, ws, out);

    k_scan<<<1, 256, 0, stream>>>(cs, ws);
    k_fill<<<NROWS / 256, 256, 0, stream>>>(ws);
    k_gather_seg<<<4608, 256, 0, stream>>>(x, ws);
    k_final<<<KDIM, 64, 0, stream>>>(ema_w, ws, out);
}

// Round 10
// 308.738 us; speedup vs baseline: 2.1809x; 1.0624x over previous
//
#include <hip/hip_runtime.h>
#include <cfloat>
#include <cmath>

#define NROWS 65536
#define DDIM 256
#define KDIM 4096

typedef short bf16x8 __attribute__((ext_vector_type(8)));
typedef float f32x4 __attribute__((ext_vector_type(4)));

constexpr float EPSV = 1e-5f;
constexpr float DECAYV = 0.99f;
constexpr float MOMV = 0.1f;
constexpr float DELTA = 0.5f;   // bf16 noise (~0.2) + pack trunc (0.25); 0.4 eff. passed r3-5
constexpr int CAP = 16;
constexpr int SEG = 128;        // rows per gather segment

// ---------------- workspace layout (float offsets) ----------------
constexpr size_t WS_CNT     = 0;                               // int[N] cand counts (zeroed)
constexpr size_t WS_NFLAG   = WS_CNT + NROWS;                  // int[1]+pad (zeroed)
constexpr size_t WS_HIST    = WS_NFLAG + 64;                   // int[K] (zeroed)
constexpr size_t WS_ZEND    = WS_HIST + KDIM;                  // end of zeroed region
constexpr size_t WS_START   = WS_ZEND;                         // int[K]
constexpr size_t WS_FILLPOS = WS_START + KDIM;                 // int[K]
constexpr size_t WS_SEGSTART= WS_FILLPOS + KDIM;               // int[K+64]
constexpr size_t WS_NSEG    = WS_SEGSTART + KDIM + 64;         // int[1]+pad
constexpr size_t WS_SEGLIST = WS_NSEG + 64;                    // int[4608+pad]
constexpr size_t WS_PARTSUM = WS_SEGLIST + 4672;               // [2048][256]
constexpr size_t WS_PARTSQ  = WS_PARTSUM + 2048 * DDIM;        // [2048][256]
constexpr size_t WS_MIDSUM  = WS_PARTSQ + 2048 * DDIM;         // [256][256]
constexpr size_t WS_MIDSQ   = WS_MIDSUM + 256 * DDIM;          // [256][256]
constexpr size_t WS_MEAN    = WS_MIDSQ + 256 * DDIM;           // [256]
constexpr size_t WS_RSTD    = WS_MEAN + DDIM;                  // [256]
constexpr size_t WS_NRMEAN  = WS_RSTD + DDIM;                  // [256]
constexpr size_t WS_NRVAR   = WS_NRMEAN + DDIM;                // [256]
constexpr size_t WS_BVEC    = WS_NRVAR + DDIM;                 // [4096]
constexpr size_t WS_NCSRAW  = WS_BVEC + KDIM;                  // [4096]
constexpr size_t WS_NTOT    = WS_NCSRAW + KDIM;                // [1]+pad
constexpr size_t WS_ROWINFO = WS_NTOT + 64;                    // float2[N][4] packed (v1,v2)
constexpr size_t WS_IDX     = WS_ROWINFO + 8 * (size_t)NROWS;  // int[N]
constexpr size_t WS_ROWTHR  = WS_IDX + NROWS;                  // float[N]
constexpr size_t WS_FLAG    = WS_ROWTHR + NROWS;               // int[N]
constexpr size_t WS_ROWLIST = WS_FLAG + NROWS;                 // int[N]
constexpr size_t WS_CAND    = WS_ROWLIST + NROWS;              // int[N*CAP]
constexpr size_t WS_DWPART  = WS_CAND;                         // ALIAS: float[4608][256] over CAND+EPROW (dead by then)
constexpr size_t WS_EPROW   = WS_CAND + (size_t)NROWS * CAP;   // float[K][D] (+e', fp32)
constexpr size_t WS_EIMG    = WS_EPROW + (size_t)KDIM * DDIM;  // bf16 image of -2*e', 2MB
constexpr size_t WS_XIMG    = WS_EIMG + 524288;                // bf16 X image 32MB

// ---------------- output layout (float offsets) ----------------
constexpr size_t O_IDX   = 0;
constexpr size_t O_EMB   = NROWS;
constexpr size_t O_EOUT  = O_EMB + (size_t)KDIM * DDIM;
constexpr size_t O_CS    = O_EOUT + (size_t)KDIM * DDIM;
constexpr size_t O_EMAW  = O_CS + KDIM;
constexpr size_t O_RMEAN = O_EMAW + (size_t)KDIM * DDIM;
constexpr size_t O_RVAR  = O_RMEAN + DDIM;

__device__ inline unsigned bfpack(float a, float b) {   // RNE f32->bf16 pair
    unsigned ua = __float_as_uint(a), ub = __float_as_uint(b);
    ua = (ua + 0x7FFFu + ((ua >> 16) & 1u)) >> 16;
    ub = (ub + 0x7FFFu + ((ub >> 16) & 1u)) & 0xFFFF0000u;
    return (ua & 0xFFFFu) | ub;
}

__device__ inline float unpackval(float p) {            // strip idx bits -> value
    return __uint_as_float(__float_as_uint(p) & 0xFFFFF000u);
}

#define GLOAD_LDS16(g, l) __builtin_amdgcn_global_load_lds(                       \
        (const __attribute__((address_space(1))) void*)(g),                        \
        (__attribute__((address_space(3))) void*)(l), 16, 0, 0)

// ===== K1: BN partial sums + fused x -> bf16 rotated image (float4) =====
__global__ __launch_bounds__(256) void k_bnpack(const float* __restrict__ x,
                                                float* __restrict__ ws) {
    const int t = threadIdx.x;
    const int q = t & 63, g = t >> 6;
    const int r0 = blockIdx.x * 128 + g * 32;
    char* ximg = (char*)(ws + WS_XIMG);
    const float4* x4 = (const float4*)x;
    float4 s = make_float4(0.f, 0.f, 0.f, 0.f);
    float4 sq = make_float4(0.f, 0.f, 0.f, 0.f);
#pragma unroll 4
    for (int i = 0; i < 32; ++i) {
        const int r = r0 + i;
        const float4 v = x4[(size_t)r * 64 + q];
        s.x += v.x; s.y += v.y; s.z += v.z; s.w += v.w;
        sq.x += v.x * v.x; sq.y += v.y * v.y; sq.z += v.z * v.z; sq.w += v.w * v.w;
        const int db = (8 * q + ((r & 15) << 5)) & 511;
        *(uint2*)(ximg + (size_t)r * 512 + db) = make_uint2(bfpack(v.x, v.y), bfpack(v.z, v.w));
    }
    const size_t p = (size_t)(blockIdx.x * 4 + g) * 64 + q;
    ((float4*)(ws + WS_PARTSUM))[p] = s;
    ((float4*)(ws + WS_PARTSQ))[p]  = sq;
}

// ===== K1b: reduce 2048 partials -> 256 =====
__global__ __launch_bounds__(256) void k_bn_mid(float* __restrict__ ws) {
    const int d = threadIdx.x, j = blockIdx.x;
    float s = 0.f, q = 0.f;
#pragma unroll
    for (int i = 0; i < 8; ++i) {
        s += ws[WS_PARTSUM + (size_t)(j * 8 + i) * DDIM + d];
        q += ws[WS_PARTSQ  + (size_t)(j * 8 + i) * DDIM + d];
    }
    ws[WS_MIDSUM + (size_t)j * DDIM + d] = s;
    ws[WS_MIDSQ  + (size_t)j * DDIM + d] = q;
}

// ===== K2: finalize BN stats =====
__global__ __launch_bounds__(256) void k_bn_final(const float* __restrict__ rmean_in,
                                                  const float* __restrict__ rvar_in,
                                                  float* __restrict__ ws,
                                                  float* __restrict__ out) {
    const int d = threadIdx.x;
    float s = 0.f, sq = 0.f;
    for (int b = 0; b < 256; ++b) {
        s  += ws[WS_MIDSUM + (size_t)b * DDIM + d];
        sq += ws[WS_MIDSQ  + (size_t)b * DDIM + d];
    }
    const float mean = s / (float)NROWS;
    float var = sq / (float)NROWS - mean * mean;
    var = fmaxf(var, 0.f);
    const float rstd = 1.0f / sqrtf(var + EPSV);
    const float nrm  = (1.0f - MOMV) * rmean_in[d] + MOMV * mean;
    const float varu = var * ((float)NROWS / (float)(NROWS - 1));
    const float nrv  = (1.0f - MOMV) * rvar_in[d] + MOMV * varu;
    ws[WS_MEAN + d] = mean;
    ws[WS_RSTD + d] = rstd;
    ws[WS_NRMEAN + d] = nrm;
    ws[WS_NRVAR + d] = nrv;
    out[O_RMEAN + d] = nrm;
    out[O_RVAR + d] = nrv;
}

// ===== K3: e' rows (fp32) + bf16 image of -2*e' + b_k (one wave per k) =====
// Image holds -2*e' so MFMA with acc init = b_k yields s = b_k - 2*x.e' directly.
__global__ __launch_bounds__(256) void k_eprime(const float* __restrict__ emb,
                                                float* __restrict__ ws) {
    const int t = threadIdx.x, l = t & 63, w = t >> 6;
    const int k = blockIdx.x * 4 + w;
    const float4 em = ((const float4*)emb)[(size_t)k * 64 + l];
    const float4 rs = ((const float4*)(ws + WS_RSTD))[l];
    const float4 mn = ((const float4*)(ws + WS_MEAN))[l];
    float4 e;
    e.x = em.x * rs.x; e.y = em.y * rs.y; e.z = em.z * rs.z; e.w = em.w * rs.w;
    ((float4*)(ws + WS_EPROW))[(size_t)k * 64 + l] = e;
    char* img = (char*)(ws + WS_EIMG);
    const int db = (8 * l + ((k & 15) << 5)) & 511;
    *(uint2*)(img + (size_t)k * 512 + db) =
        make_uint2(bfpack(-2.f * e.x, -2.f * e.y), bfpack(-2.f * e.z, -2.f * e.w));
    float red = em.x * em.x + 2.f * mn.x * e.x + em.y * em.y + 2.f * mn.y * e.y
              + em.z * em.z + 2.f * mn.z * e.z + em.w * em.w + 2.f * mn.w * e.w;
    red += __shfl_xor(red, 32); red += __shfl_xor(red, 16); red += __shfl_xor(red, 8);
    red += __shfl_xor(red, 4);  red += __shfl_xor(red, 2);  red += __shfl_xor(red, 1);
    if (l == 0) ws[WS_BVEC + k] = red;
}

// ===== K4: single-pass MFMA GEMM, bias-in-acc, packed med3 top-2 =====
// 2048 blocks = 512 row-tiles x 4 col-quarters; 4 waves x 32 rows each.
// acc inits to b_k (same cost as 0-init) -> MFMA output IS the distance; the
// per-element fmaf disappears. b_k loads pipelined one chunk ahead.
__global__ __launch_bounds__(256, 4) void k_gemm_min(float* __restrict__ ws) {
    extern __shared__ char smem[];      // 2 x 16384
    const int t = threadIdx.x, lane = t & 63, w = t >> 6;
    const int l4 = lane & 15, kg = lane >> 4;
    const int tile = blockIdx.x >> 2;
    const int cq   = blockIdx.x & 3;
    const int rowbase = tile * 128 + w * 32;
    const char* ximg = (const char*)(ws + WS_XIMG);
    const char* eimg = (const char*)(ws + WS_EIMG) + (size_t)cq * 524288;  // 1024 cols
    const float* bvec = ws + WS_BVEC;

    // A fragments: rows rowbase + m*16 + l4, all 8 k-steps (rotated image)
    bf16x8 a[2][8];
#pragma unroll
    for (int m = 0; m < 2; ++m) {
        const char* rp = ximg + (size_t)(rowbase + m * 16 + l4) * 512;
#pragma unroll
        for (int ts = 0; ts < 8; ++ts) {
            const int byte = ((kg * 16 + ts * 64) + (l4 << 5)) & 511;
            a[m][ts] = *(const bf16x8*)(rp + byte);
        }
    }

    float b1f[2][4], b2f[2][4];
#pragma unroll
    for (int m = 0; m < 2; ++m)
#pragma unroll
        for (int r = 0; r < 4; ++r) { b1f[m][r] = FLT_MAX; b2f[m][r] = FLT_MAX; }

    // prologue: stage chunk 0 (16KB) + bias for chunk 0
#pragma unroll
    for (int rr = 0; rr < 4; ++rr) {
        const int off = rr * 4096 + w * 1024;
        GLOAD_LDS16(eimg + off + lane * 16, smem + off);
    }
    float bc0 = bvec[cq * 1024 + l4];
    float bc1 = bvec[cq * 1024 + 16 + l4];
    __syncthreads();

    for (int ch = 0; ch < 32; ++ch) {
        const char* cur = smem + (ch & 1) * 16384;
        float bn0 = 0.f, bn1 = 0.f;
        if (ch + 1 < 32) {
            const char* src = eimg + (size_t)(ch + 1) * 16384;
            char* nb = smem + ((ch + 1) & 1) * 16384;
#pragma unroll
            for (int rr = 0; rr < 4; ++rr) {
                const int off = rr * 4096 + w * 1024;
                GLOAD_LDS16(src + off + lane * 16, nb + off);
            }
            bn0 = bvec[cq * 1024 + (ch + 1) * 32 + l4];
            bn1 = bvec[cq * 1024 + (ch + 1) * 32 + 16 + l4];
        }

        f32x4 acc[2][2];
        acc[0][0] = (f32x4){bc0, bc0, bc0, bc0};
        acc[0][1] = (f32x4){bc1, bc1, bc1, bc1};
        acc[1][0] = acc[0][0];
        acc[1][1] = acc[0][1];

#pragma unroll
        for (int ts = 0; ts < 8; ++ts) {
            const int rot = ((kg * 16 + ts * 64) + (l4 << 5)) & 511;
            bf16x8 bfr[2];
#pragma unroll
            for (int n = 0; n < 2; ++n)
                bfr[n] = *(const bf16x8*)(cur + (n * 16 + l4) * 512 + rot);
#pragma unroll
            for (int m = 0; m < 2; ++m)
#pragma unroll
                for (int n = 0; n < 2; ++n)
                    acc[m][n] = __builtin_amdgcn_mfma_f32_16x16x32_bf16(a[m][ts], bfr[n], acc[m][n], 0, 0, 0);
        }

#pragma unroll
        for (int n = 0; n < 2; ++n) {
            const unsigned col = (unsigned)(cq * 1024 + ch * 32 + n * 16 + l4);
#pragma unroll
            for (int m = 0; m < 2; ++m)
#pragma unroll
                for (int r = 0; r < 4; ++r) {
                    const float p = __uint_as_float(
                        (__float_as_uint(acc[m][n][r]) & 0xFFFFF000u) | col);  // v_and_or_b32
                    b2f[m][r] = __builtin_amdgcn_fmed3f(p, b1f[m][r], b2f[m][r]);
                    b1f[m][r] = fminf(p, b1f[m][r]);
                }
        }
        bc0 = bn0; bc1 = bn1;
        __syncthreads();   // drains prefetch + protects cur reuse
    }

    // merge top-2 across the 16 l4-lanes holding each row; write packed pair
    float2* rowinfo = (float2*)(ws + WS_ROWINFO);
#pragma unroll
    for (int m = 0; m < 2; ++m)
#pragma unroll
        for (int r = 0; r < 4; ++r) {
            float v1 = b1f[m][r], v2 = b2f[m][r];
#pragma unroll
            for (int st = 1; st < 16; st <<= 1) {
                const float o1 = __shfl_xor(v1, st);
                const float o2 = __shfl_xor(v2, st);
                const float mm = fminf(v2, o2);
                v2 = __builtin_amdgcn_fmed3f(v1, o1, mm);
                v1 = fminf(v1, o1);
            }
            if (l4 == 0) {
                const int row = rowbase + m * 16 + kg * 4 + r;
                rowinfo[(size_t)row * 4 + cq] = make_float2(v1, v2);
            }
        }
}

// ===== K5: merge 4 col-quarter partials, flag close rows, hist clear rows =====
__global__ __launch_bounds__(256) void k_flag(float* __restrict__ ws,
                                              float* __restrict__ out) {
    const int r = blockIdx.x * 256 + threadIdx.x;
    const float2* rowinfo = (const float2*)(ws + WS_ROWINFO);
    float2 q = rowinfo[(size_t)r * 4];
    float v1 = q.x, v2 = q.y;
#pragma unroll
    for (int c = 1; c < 4; ++c) {
        q = rowinfo[(size_t)r * 4 + c];
        const float mm = fminf(v2, q.y);
        v2 = __builtin_amdgcn_fmed3f(v1, q.x, mm);
        v1 = fminf(v1, q.x);
    }
    const float v1v = unpackval(v1);
    const int   i1  = (int)(__float_as_uint(v1) & 0xFFFu);
    ws[WS_ROWTHR + r] = v1v + DELTA;
    if (unpackval(v2) - v1v <= DELTA) {
        const int pos = atomicAdd((int*)(ws + WS_NFLAG), 1);
        ((int*)(ws + WS_FLAG))[pos] = r;
    } else {
        out[O_IDX + r] = (float)i1;
        ((int*)(ws + WS_IDX))[r] = i1;
        atomicAdd((int*)(ws + WS_HIST) + i1, 1);
    }
}

// ===== K6: candidate-append mini-GEMM over flagged rows, col-sliced x8 =====
__global__ __launch_bounds__(256) void k_cand(float* __restrict__ ws) {
    extern __shared__ char smem[];      // 2 x 16384
    const int t = threadIdx.x, lane = t & 63, w = t >> 6;
    const int l4 = lane & 15, kg = lane >> 4;
    const char* ximg = (const char*)(ws + WS_XIMG);
    const char* eimg0 = (const char*)(ws + WS_EIMG);
    const float* bvec = ws + WS_BVEC;
    const int* flag = (const int*)(ws + WS_FLAG);
    int* cnt = (int*)(ws + WS_CNT);
    int* cand = (int*)(ws + WS_CAND);
    const int nflag = *(const int*)(ws + WS_NFLAG);
    if (nflag == 0) return;
    const int ntiles = (nflag + 127) >> 7;
    const int nitems = ntiles * 8;

    for (int item = blockIdx.x; item < nitems; item += gridDim.x) {
        const int tile = item >> 3, slice = item & 7;
        const int base = tile * 128 + w * 32;
        const char* eimg = eimg0 + (size_t)slice * 262144;   // 512 cols per slice
        bf16x8 a[2][8];
        int frow[2][4];
        float thr[2][4];
#pragma unroll
        for (int m = 0; m < 2; ++m) {
            const int ia = base + m * 16 + l4;
            const int rowa = flag[ia < nflag ? ia : (nflag - 1)];
            const char* rp = ximg + (size_t)rowa * 512;
#pragma unroll
            for (int ts = 0; ts < 8; ++ts) {
                const int byte = ((kg * 16 + ts * 64) + ((rowa & 15) << 5)) & 511;
                a[m][ts] = *(const bf16x8*)(rp + byte);
            }
#pragma unroll
            for (int r = 0; r < 4; ++r) {
                const int ie = base + m * 16 + kg * 4 + r;
                const bool val = ie < nflag;
                const int rowe = flag[val ? ie : (nflag - 1)];
                frow[m][r] = rowe;
                thr[m][r] = val ? ws[WS_ROWTHR + rowe] : -FLT_MAX;
            }
        }
#pragma unroll
        for (int rr = 0; rr < 4; ++rr) {
            const int off = rr * 4096 + w * 1024;
            GLOAD_LDS16(eimg + off + lane * 16, smem + off);
        }
        __syncthreads();

        for (int ch = 0; ch < 16; ++ch) {
            const char* cur = smem + (ch & 1) * 16384;
            if (ch + 1 < 16) {
                const char* src = eimg + (size_t)(ch + 1) * 16384;
                char* nb = smem + ((ch + 1) & 1) * 16384;
#pragma unroll
                for (int rr = 0; rr < 4; ++rr) {
                    const int off = rr * 4096 + w * 1024;
                    GLOAD_LDS16(src + off + lane * 16, nb + off);
                }
            }
            const float bc0 = bvec[slice * 512 + ch * 32 + l4];
            const float bc1 = bvec[slice * 512 + ch * 32 + 16 + l4];
            f32x4 acc[2][2];
            acc[0][0] = (f32x4){bc0, bc0, bc0, bc0};
            acc[0][1] = (f32x4){bc1, bc1, bc1, bc1};
            acc[1][0] = acc[0][0];
            acc[1][1] = acc[0][1];
#pragma unroll
            for (int ts = 0; ts < 8; ++ts) {
                const int rot = ((kg * 16 + ts * 64) + (l4 << 5)) & 511;
                bf16x8 bfr[2];
#pragma unroll
                for (int n = 0; n < 2; ++n)
                    bfr[n] = *(const bf16x8*)(cur + (n * 16 + l4) * 512 + rot);
#pragma unroll
                for (int m = 0; m < 2; ++m)
#pragma unroll
                    for (int n = 0; n < 2; ++n)
                        acc[m][n] = __builtin_amdgcn_mfma_f32_16x16x32_bf16(a[m][ts], bfr[n], acc[m][n], 0, 0, 0);
            }
#pragma unroll
            for (int n = 0; n < 2; ++n) {
                const int col = slice * 512 + ch * 32 + n * 16 + l4;
#pragma unroll
                for (int m = 0; m < 2; ++m)
#pragma unroll
                    for (int r = 0; r < 4; ++r) {
                        const float s = acc[m][n][r];
                        if (s <= thr[m][r]) {
                            const int rr2 = frow[m][r];
                            const int pos = atomicAdd(&cnt[rr2], 1);
                            if (pos < CAP) cand[(size_t)rr2 * CAP + pos] = col;
                        }
                    }
            }
            __syncthreads();
        }
    }
}

// ===== K7: exact fp32 resolve for flagged rows (+hist) =====
__global__ __launch_bounds__(256) void k_resolve_f(const float* __restrict__ x,
                                                   float* __restrict__ ws,
                                                   float* __restrict__ out) {
    const int t = threadIdx.x, lane = t & 63;
    const int gw = (blockIdx.x * 256 + t) >> 6;     // 1024 waves
    const int nflag = *(const int*)(ws + WS_NFLAG);
    const int* flag = (const int*)(ws + WS_FLAG);
    const int* cnt = (const int*)(ws + WS_CNT);
    const int* cand = (const int*)(ws + WS_CAND);
    const float* eprow = ws + WS_EPROW;
    const float* bvec = ws + WS_BVEC;
    int* idx_int = (int*)(ws + WS_IDX);
    for (int i = gw; i < nflag; i += 1024) {
        const int row = flag[i];
        const float4 xr = ((const float4*)(x + (size_t)row * DDIM))[lane];
        const int n = cnt[row];
        float bestv = FLT_MAX;
        int bestk = KDIM;
        if (n >= 1 && n <= CAP) {
            for (int c = 0; c < n; ++c) {
                const int k = cand[(size_t)row * CAP + c];
                const float4 er = ((const float4*)(eprow + (size_t)k * DDIM))[lane];
                float p = xr.x * er.x + xr.y * er.y + xr.z * er.z + xr.w * er.w;
                p += __shfl_xor(p, 32); p += __shfl_xor(p, 16); p += __shfl_xor(p, 8);
                p += __shfl_xor(p, 4);  p += __shfl_xor(p, 2);  p += __shfl_xor(p, 1);
                const float s = fmaf(-2.f, p, bvec[k]);
                if (s < bestv || (s == bestv && k < bestk)) { bestv = s; bestk = k; }
            }
        } else {   // overflow / safety fallback: exact full scan
            for (int k = 0; k < KDIM; ++k) {
                const float4 er = ((const float4*)(eprow + (size_t)k * DDIM))[lane];
                float p = xr.x * er.x + xr.y * er.y + xr.z * er.z + xr.w * er.w;
                p += __shfl_xor(p, 32); p += __shfl_xor(p, 16); p += __shfl_xor(p, 8);
                p += __shfl_xor(p, 4);  p += __shfl_xor(p, 2);  p += __shfl_xor(p, 1);
                const float s = fmaf(-2.f, p, bvec[k]);
                if (s < bestv || (s == bestv && k < bestk)) { bestv = s; bestk = k; }
            }
        }
        if (lane == 0) {
            out[O_IDX + row] = (float)bestk;
            idx_int[row] = bestk;
            atomicAdd((int*)(ws + WS_HIST) + bestk, 1);
        }
    }
}

// ===== K8: dual prefix sums + segment descriptors + EMA cluster size =====
__global__ __launch_bounds__(256) void k_scan(const float* __restrict__ cs_in,
                                              float* __restrict__ ws) {
    __shared__ int lsum[256], lseg[256];
    __shared__ float redf[256];
    const int t = threadIdx.x;
    const int* hist = (const int*)(ws + WS_HIST);
    int h[16];
    int s = 0, g = 0;
#pragma unroll
    for (int i = 0; i < 16; ++i) {
        h[i] = hist[t * 16 + i];
        s += h[i];
        g += (h[i] + SEG - 1) / SEG;
    }
    lsum[t] = s; lseg[t] = g;
    __syncthreads();
    int v = s, u = g;
    for (int off = 1; off < 256; off <<= 1) {
        const int av = (t >= off) ? lsum[t - off] : 0;
        const int au = (t >= off) ? lseg[t - off] : 0;
        __syncthreads();
        v += av; u += au;
        lsum[t] = v; lseg[t] = u;
        __syncthreads();
    }
    int runs = v - s, rung = u - g;
    int* start = (int*)(ws + WS_START);
    int* fillpos = (int*)(ws + WS_FILLPOS);
    int* segst = (int*)(ws + WS_SEGSTART);
    int* seglist = (int*)(ws + WS_SEGLIST);
    float emapart = 0.f;
#pragma unroll
    for (int i = 0; i < 16; ++i) {
        const int k = t * 16 + i;
        start[k] = runs;
        fillpos[k] = runs;
        segst[k] = rung;
        const int ns = (h[i] + SEG - 1) / SEG;
        for (int j = 0; j < ns; ++j) seglist[rung + j] = (k << 10) | j;
        runs += h[i];
        rung += ns;
        const float ncs = cs_in[k] * DECAYV + (1.0f - DECAYV) * (float)h[i];
        ws[WS_NCSRAW + k] = ncs;
        emapart += ncs;
    }
    if (t == 255) {
        segst[KDIM] = rung;
        *(int*)(ws + WS_NSEG) = rung;
    }
    redf[t] = emapart;
    __syncthreads();
    for (int ss = 128; ss > 0; ss >>= 1) { if (t < ss) redf[t] += redf[t + ss]; __syncthreads(); }
    if (t == 0) ws[WS_NTOT] = redf[0];
}

// ===== K8c: fill per-cluster row lists =====
__global__ __launch_bounds__(256) void k_fill(float* __restrict__ ws) {
    const int r = blockIdx.x * 256 + threadIdx.x;
    const int k = ((const int*)(ws + WS_IDX))[r];
    const int pos = atomicAdd((int*)(ws + WS_FILLPOS) + k, 1);
    ((int*)(ws + WS_ROWLIST))[pos] = r;
}

// ===== K8e: per-segment gather partial sums, float4 + 4-group combine =====
__global__ __launch_bounds__(256) void k_gather_seg(const float* __restrict__ x,
                                                    float* __restrict__ ws) {
    __shared__ float4 ls[4][64];
    const int b = blockIdx.x;
    if (b >= *(const int*)(ws + WS_NSEG)) return;
    const int e = ((const int*)(ws + WS_SEGLIST))[b];
    const int k = e >> 10, j = e & 1023;
    const int base = ((const int*)(ws + WS_START))[k];
    const int n = ((const int*)(ws + WS_HIST))[k];
    const int st = base + j * SEG;
    const int en = min(st + SEG, base + n);
    const int* rowlist = (const int*)(ws + WS_ROWLIST);
    const int t = threadIdx.x, q = t & 63, g = t >> 6;
    const float4* x4 = (const float4*)x;
    float4 s = make_float4(0.f, 0.f, 0.f, 0.f);
    for (int i = st + g; i < en; i += 4) {
        const float4 v = x4[(size_t)rowlist[i] * 64 + q];
        s.x += v.x; s.y += v.y; s.z += v.z; s.w += v.w;
    }
    ls[g][q] = s;
    __syncthreads();
    if (t < 64) {
        const float4 a0 = ls[0][t], a1 = ls[1][t], a2 = ls[2][t], a3 = ls[3][t];
        float4 r;
        r.x = (a0.x + a1.x) + (a2.x + a3.x);
        r.y = (a0.y + a1.y) + (a2.y + a3.y);
        r.z = (a0.z + a1.z) + (a2.z + a3.z);
        r.w = (a0.w + a1.w) + (a2.w + a3.w);
        ((float4*)(ws + WS_DWPART))[(size_t)b * 64 + t] = r;
    }
}

// ===== K9: streaming finalize [K,D] outputs (float4, one wave per k) =====
__global__ __launch_bounds__(64) void k_final(const float* __restrict__ ema_w,
                                              const float* __restrict__ ws,
                                              float* __restrict__ out) {
    const int k = blockIdx.x;   // 4096 blocks
    const int q = threadIdx.x;  // d-quad
    const int* segst = (const int*)(ws + WS_SEGSTART);
    const int ss = segst[k];
    const int ns = segst[k + 1] - ss;
    const float4* dwpart = (const float4*)(ws + WS_DWPART);
    float4 a = make_float4(0.f, 0.f, 0.f, 0.f);
    for (int j = 0; j < ns; ++j) {
        const float4 v = dwpart[(size_t)(ss + j) * 64 + q];
        a.x += v.x; a.y += v.y; a.z += v.z; a.w += v.w;
    }
    const int n = ((const int*)(ws + WS_HIST))[k];
    const float ntot = ws[WS_NTOT];
    const float ncs  = (ws[WS_NCSRAW + k] + 1e-5f) / (ntot + (float)KDIM * 1e-5f) * ntot;
    const float4 mn = ((const float4*)(ws + WS_MEAN))[q];
    const float4 rs = ((const float4*)(ws + WS_RSTD))[q];
    const float4 nrv = ((const float4*)(ws + WS_NRVAR))[q];
    const float4 nrm = ((const float4*)(ws + WS_NRMEAN))[q];
    const float4 ew = ((const float4*)ema_w)[(size_t)k * 64 + q];
    const float fn = (float)n;
    float4 nwv, nembv, eov;
    nwv.x = ew.x * DECAYV + (1.f - DECAYV) * ((a.x - fn * mn.x) * rs.x);
    nwv.y = ew.y * DECAYV + (1.f - DECAYV) * ((a.y - fn * mn.y) * rs.y);
    nwv.z = ew.z * DECAYV + (1.f - DECAYV) * ((a.z - fn * mn.z) * rs.z);
    nwv.w = ew.w * DECAYV + (1.f - DECAYV) * ((a.w - fn * mn.w) * rs.w);
    const float inv = 1.0f / ncs;
    nembv.x = nwv.x * inv; nembv.y = nwv.y * inv;
    nembv.z = nwv.z * inv; nembv.w = nwv.w * inv;
    eov.x = nembv.x * sqrtf(nrv.x + EPSV) + nrm.x;
    eov.y = nembv.y * sqrtf(nrv.y + EPSV) + nrm.y;
    eov.z = nembv.z * sqrtf(nrv.z + EPSV) + nrm.z;
    eov.w = nembv.w * sqrtf(nrv.w + EPSV) + nrm.w;
    ((float4*)(out + O_EMB))[(size_t)k * 64 + q]  = nembv;
    ((float4*)(out + O_EOUT))[(size_t)k * 64 + q] = eov;
    ((float4*)(out + O_EMAW))[(size_t)k * 64 + q] = nwv;
    if (q == 0) out[O_CS + k] = ncs;
}

// ===== launcher =====
extern "C" void kernel_launch(void* const* d_in, const int* in_sizes, int n_in,
                              void* d_out, int out_size, void* d_ws, size_t ws_size,
                              hipStream_t stream) {
    const float* x     = (const float*)d_in[0];
    const float* emb   = (const float*)d_in[1];
    const float* cs    = (const float*)d_in[2];
    const float* ema_w = (const float*)d_in[3];
    const float* rmean = (const float*)d_in[4];
    const float* rvar  = (const float*)d_in[5];
    float* out = (float*)d_out;
    float* ws  = (float*)d_ws;

    // zero cnt + nflag + hist (contiguous at ws base, ~280 KB)
    hipMemsetAsync(ws, 0, WS_ZEND * sizeof(float), stream);

    k_bnpack<<<512, 256, 0, stream>>>(x, ws);
    k_bn_mid<<<256, 256, 0, stream>>>(ws);
    k_bn_final<<<1, 256, 0, stream>>>(rmean, rvar, ws, out);
    k_eprime<<<KDIM / 4, 256, 0, stream>>>(emb, ws);

    constexpr int LDSB = 32768;
    k_gemm_min<<<2048, 256, LDSB, stream>>>(ws);
    k_flag<<<NROWS / 256, 256, 0, stream>>>(ws, out);
    k_cand<<<512, 256, LDSB, stream>>>(ws);
    k_resolve_f<<<256, 256, 0, stream>>>(x, ws, out);

    k_scan<<<1, 256, 0, stream>>>(cs, ws);
    k_fill<<<NROWS / 256, 256, 0, stream>>>(ws);
    k_gather_seg<<<4608, 256, 0, stream>>>(x, ws);
    k_final<<<KDIM, 64, 0, stream>>>(ema_w, ws, out);
}

// Round 11
// 304.837 us; speedup vs baseline: 2.2088x; 1.0128x over previous
//
#include <hip/hip_runtime.h>
#include <cfloat>
#include <cmath>

#define NROWS 65536
#define DDIM 256
#define KDIM 4096

typedef short bf16x8 __attribute__((ext_vector_type(8)));
typedef float f32x4 __attribute__((ext_vector_type(4)));

constexpr float EPSV = 1e-5f;
constexpr float DECAYV = 0.99f;
constexpr float MOMV = 0.1f;
constexpr float DELTA = 0.5f;   // bf16 noise (~0.2) + pack trunc (0.25); 0.4 eff. passed r3-5
constexpr int CAP = 16;
constexpr int SEG = 128;        // rows per gather segment

// ---------------- workspace layout (float offsets) ----------------
constexpr size_t WS_CNT     = 0;                               // int[N] cand counts (zeroed)
constexpr size_t WS_NFLAG   = WS_CNT + NROWS;                  // int[1]+pad (zeroed)
constexpr size_t WS_HIST    = WS_NFLAG + 64;                   // int[K] (zeroed)
constexpr size_t WS_ZEND    = WS_HIST + KDIM;                  // end of zeroed region
constexpr size_t WS_START   = WS_ZEND;                         // int[K]
constexpr size_t WS_FILLPOS = WS_START + KDIM;                 // int[K]
constexpr size_t WS_SEGSTART= WS_FILLPOS + KDIM;               // int[K+64]
constexpr size_t WS_NSEG    = WS_SEGSTART + KDIM + 64;         // int[1]+pad
constexpr size_t WS_SEGLIST = WS_NSEG + 64;                    // int[4608+pad]
constexpr size_t WS_PARTSUM = WS_SEGLIST + 4672;               // [2048][256]
constexpr size_t WS_PARTSQ  = WS_PARTSUM + 2048 * DDIM;        // [2048][256]
constexpr size_t WS_MIDSUM  = WS_PARTSQ + 2048 * DDIM;         // [256][256]
constexpr size_t WS_MIDSQ   = WS_MIDSUM + 256 * DDIM;          // [256][256]
constexpr size_t WS_MEAN    = WS_MIDSQ + 256 * DDIM;           // [256]
constexpr size_t WS_RSTD    = WS_MEAN + DDIM;                  // [256]
constexpr size_t WS_NRMEAN  = WS_RSTD + DDIM;                  // [256]
constexpr size_t WS_NRVAR   = WS_NRMEAN + DDIM;                // [256]
constexpr size_t WS_BVEC    = WS_NRVAR + DDIM;                 // [4096]
constexpr size_t WS_NCSRAW  = WS_BVEC + KDIM;                  // [4096]
constexpr size_t WS_NTOT    = WS_NCSRAW + KDIM;                // [1]+pad
constexpr size_t WS_ROWINFO = WS_NTOT + 64;                    // float2[N][4] packed (v1,v2)
constexpr size_t WS_IDX     = WS_ROWINFO + 8 * (size_t)NROWS;  // int[N]
constexpr size_t WS_ROWTHR  = WS_IDX + NROWS;                  // float[N]
constexpr size_t WS_FLAG    = WS_ROWTHR + NROWS;               // int[N]
constexpr size_t WS_ROWLIST = WS_FLAG + NROWS;                 // int[N]
constexpr size_t WS_CAND    = WS_ROWLIST + NROWS;              // int[N*CAP]
constexpr size_t WS_DWPART  = WS_CAND;                         // ALIAS: float[4608][256] over CAND+EPROW (dead by then)
constexpr size_t WS_EPROW   = WS_CAND + (size_t)NROWS * CAP;   // float[K][D] (+e', fp32)
constexpr size_t WS_EIMG    = WS_EPROW + (size_t)KDIM * DDIM;  // bf16 image of -2*e', 2MB
constexpr size_t WS_XIMG    = WS_EIMG + 524288;                // bf16 X image 32MB

// ---------------- output layout (float offsets) ----------------
constexpr size_t O_IDX   = 0;
constexpr size_t O_EMB   = NROWS;
constexpr size_t O_EOUT  = O_EMB + (size_t)KDIM * DDIM;
constexpr size_t O_CS    = O_EOUT + (size_t)KDIM * DDIM;
constexpr size_t O_EMAW  = O_CS + KDIM;
constexpr size_t O_RMEAN = O_EMAW + (size_t)KDIM * DDIM;
constexpr size_t O_RVAR  = O_RMEAN + DDIM;

__device__ inline unsigned bfpack(float a, float b) {   // RNE f32->bf16 pair
    unsigned ua = __float_as_uint(a), ub = __float_as_uint(b);
    ua = (ua + 0x7FFFu + ((ua >> 16) & 1u)) >> 16;
    ub = (ub + 0x7FFFu + ((ub >> 16) & 1u)) & 0xFFFF0000u;
    return (ua & 0xFFFFu) | ub;
}

__device__ inline float unpackval(float p) {            // strip idx bits -> value
    return __uint_as_float(__float_as_uint(p) & 0xFFFFF000u);
}

#define GLOAD_LDS16(g, l) __builtin_amdgcn_global_load_lds(                       \
        (const __attribute__((address_space(1))) void*)(g),                        \
        (__attribute__((address_space(3))) void*)(l), 16, 0, 0)

// ===== K1: BN partial sums + fused x -> bf16 rotated image (float4) =====
__global__ __launch_bounds__(256) void k_bnpack(const float* __restrict__ x,
                                                float* __restrict__ ws) {
    const int t = threadIdx.x;
    const int q = t & 63, g = t >> 6;
    const int r0 = blockIdx.x * 128 + g * 32;
    char* ximg = (char*)(ws + WS_XIMG);
    const float4* x4 = (const float4*)x;
    float4 s = make_float4(0.f, 0.f, 0.f, 0.f);
    float4 sq = make_float4(0.f, 0.f, 0.f, 0.f);
#pragma unroll 4
    for (int i = 0; i < 32; ++i) {
        const int r = r0 + i;
        const float4 v = x4[(size_t)r * 64 + q];
        s.x += v.x; s.y += v.y; s.z += v.z; s.w += v.w;
        sq.x += v.x * v.x; sq.y += v.y * v.y; sq.z += v.z * v.z; sq.w += v.w * v.w;
        const int db = (8 * q + ((r & 15) << 5)) & 511;
        *(uint2*)(ximg + (size_t)r * 512 + db) = make_uint2(bfpack(v.x, v.y), bfpack(v.z, v.w));
    }
    const size_t p = (size_t)(blockIdx.x * 4 + g) * 64 + q;
    ((float4*)(ws + WS_PARTSUM))[p] = s;
    ((float4*)(ws + WS_PARTSQ))[p]  = sq;
}

// ===== K1b: reduce 2048 partials -> 256 =====
__global__ __launch_bounds__(256) void k_bn_mid(float* __restrict__ ws) {
    const int d = threadIdx.x, j = blockIdx.x;
    float s = 0.f, q = 0.f;
#pragma unroll
    for (int i = 0; i < 8; ++i) {
        s += ws[WS_PARTSUM + (size_t)(j * 8 + i) * DDIM + d];
        q += ws[WS_PARTSQ  + (size_t)(j * 8 + i) * DDIM + d];
    }
    ws[WS_MIDSUM + (size_t)j * DDIM + d] = s;
    ws[WS_MIDSQ  + (size_t)j * DDIM + d] = q;
}

// ===== K2: finalize BN stats =====
__global__ __launch_bounds__(256) void k_bn_final(const float* __restrict__ rmean_in,
                                                  const float* __restrict__ rvar_in,
                                                  float* __restrict__ ws,
                                                  float* __restrict__ out) {
    const int d = threadIdx.x;
    float s = 0.f, sq = 0.f;
    for (int b = 0; b < 256; ++b) {
        s  += ws[WS_MIDSUM + (size_t)b * DDIM + d];
        sq += ws[WS_MIDSQ  + (size_t)b * DDIM + d];
    }
    const float mean = s / (float)NROWS;
    float var = sq / (float)NROWS - mean * mean;
    var = fmaxf(var, 0.f);
    const float rstd = 1.0f / sqrtf(var + EPSV);
    const float nrm  = (1.0f - MOMV) * rmean_in[d] + MOMV * mean;
    const float varu = var * ((float)NROWS / (float)(NROWS - 1));
    const float nrv  = (1.0f - MOMV) * rvar_in[d] + MOMV * varu;
    ws[WS_MEAN + d] = mean;
    ws[WS_RSTD + d] = rstd;
    ws[WS_NRMEAN + d] = nrm;
    ws[WS_NRVAR + d] = nrv;
    out[O_RMEAN + d] = nrm;
    out[O_RVAR + d] = nrv;
}

// ===== K3: e' rows (fp32) + bf16 image of -2*e' + b_k (one wave per k) =====
__global__ __launch_bounds__(256) void k_eprime(const float* __restrict__ emb,
                                                float* __restrict__ ws) {
    const int t = threadIdx.x, l = t & 63, w = t >> 6;
    const int k = blockIdx.x * 4 + w;
    const float4 em = ((const float4*)emb)[(size_t)k * 64 + l];
    const float4 rs = ((const float4*)(ws + WS_RSTD))[l];
    const float4 mn = ((const float4*)(ws + WS_MEAN))[l];
    float4 e;
    e.x = em.x * rs.x; e.y = em.y * rs.y; e.z = em.z * rs.z; e.w = em.w * rs.w;
    ((float4*)(ws + WS_EPROW))[(size_t)k * 64 + l] = e;
    char* img = (char*)(ws + WS_EIMG);
    const int db = (8 * l + ((k & 15) << 5)) & 511;
    *(uint2*)(img + (size_t)k * 512 + db) =
        make_uint2(bfpack(-2.f * e.x, -2.f * e.y), bfpack(-2.f * e.z, -2.f * e.w));
    float red = em.x * em.x + 2.f * mn.x * e.x + em.y * em.y + 2.f * mn.y * e.y
              + em.z * em.z + 2.f * mn.z * e.z + em.w * em.w + 2.f * mn.w * e.w;
    red += __shfl_xor(red, 32); red += __shfl_xor(red, 16); red += __shfl_xor(red, 8);
    red += __shfl_xor(red, 4);  red += __shfl_xor(red, 2);  red += __shfl_xor(red, 1);
    if (l == 0) ws[WS_BVEC + k] = red;
}

// ===== K4: single-pass MFMA GEMM, 64 rows/wave, bias-in-acc, med3 top-2 =====
// 1024 blocks = 256 row-tiles(256 rows) x 4 col-quarters; 4 waves x 64 rows.
// LDS B-traffic halves vs 32-row (2.15GB: 38us) and per-MFMA VALU halves ->
// MFMA (66us floor) becomes the dominant pipe. A-frags 128 VGPR; LB(256,2)
// caps at 256 VGPR (need ~215 -> no spill; round-8 spill was cap<working set).
__global__ __launch_bounds__(256, 2) void k_gemm_min(float* __restrict__ ws) {
    extern __shared__ char smem[];      // 2 x 16384
    const int t = threadIdx.x, lane = t & 63, w = t >> 6;
    const int l4 = lane & 15, kg = lane >> 4;
    const int tile = blockIdx.x >> 2;
    const int cq   = blockIdx.x & 3;
    const int rowbase = tile * 256 + w * 64;
    const char* ximg = (const char*)(ws + WS_XIMG);
    const char* eimg = (const char*)(ws + WS_EIMG) + (size_t)cq * 524288;  // 1024 cols
    const float* bvec = ws + WS_BVEC;

    // A fragments: rows rowbase + m*16 + l4, all 8 k-steps (rotated image)
    bf16x8 a[4][8];
#pragma unroll
    for (int m = 0; m < 4; ++m) {
        const char* rp = ximg + (size_t)(rowbase + m * 16 + l4) * 512;
#pragma unroll
        for (int ts = 0; ts < 8; ++ts) {
            const int byte = ((kg * 16 + ts * 64) + (l4 << 5)) & 511;
            a[m][ts] = *(const bf16x8*)(rp + byte);
        }
    }

    float b1f[4][4], b2f[4][4];
#pragma unroll
    for (int m = 0; m < 4; ++m)
#pragma unroll
        for (int r = 0; r < 4; ++r) { b1f[m][r] = FLT_MAX; b2f[m][r] = FLT_MAX; }

    // prologue: stage chunk 0 (16KB) + bias for chunk 0
#pragma unroll
    for (int rr = 0; rr < 4; ++rr) {
        const int off = rr * 4096 + w * 1024;
        GLOAD_LDS16(eimg + off + lane * 16, smem + off);
    }
    float bc0 = bvec[cq * 1024 + l4];
    float bc1 = bvec[cq * 1024 + 16 + l4];
    __syncthreads();

    for (int ch = 0; ch < 32; ++ch) {
        const char* cur = smem + (ch & 1) * 16384;
        float bn0 = 0.f, bn1 = 0.f;
        if (ch + 1 < 32) {
            const char* src = eimg + (size_t)(ch + 1) * 16384;
            char* nb = smem + ((ch + 1) & 1) * 16384;
#pragma unroll
            for (int rr = 0; rr < 4; ++rr) {
                const int off = rr * 4096 + w * 1024;
                GLOAD_LDS16(src + off + lane * 16, nb + off);
            }
            bn0 = bvec[cq * 1024 + (ch + 1) * 32 + l4];
            bn1 = bvec[cq * 1024 + (ch + 1) * 32 + 16 + l4];
        }

        f32x4 acc[4][2];
#pragma unroll
        for (int m = 0; m < 4; ++m) {
            acc[m][0] = (f32x4){bc0, bc0, bc0, bc0};
            acc[m][1] = (f32x4){bc1, bc1, bc1, bc1};
        }

#pragma unroll
        for (int ts = 0; ts < 8; ++ts) {
            const int rot = ((kg * 16 + ts * 64) + (l4 << 5)) & 511;
            bf16x8 bfr[2];
#pragma unroll
            for (int n = 0; n < 2; ++n)
                bfr[n] = *(const bf16x8*)(cur + (n * 16 + l4) * 512 + rot);
#pragma unroll
            for (int m = 0; m < 4; ++m)
#pragma unroll
                for (int n = 0; n < 2; ++n)
                    acc[m][n] = __builtin_amdgcn_mfma_f32_16x16x32_bf16(a[m][ts], bfr[n], acc[m][n], 0, 0, 0);
        }

#pragma unroll
        for (int n = 0; n < 2; ++n) {
            const unsigned col = (unsigned)(cq * 1024 + ch * 32 + n * 16 + l4);
#pragma unroll
            for (int m = 0; m < 4; ++m)
#pragma unroll
                for (int r = 0; r < 4; ++r) {
                    const float p = __uint_as_float(
                        (__float_as_uint(acc[m][n][r]) & 0xFFFFF000u) | col);  // v_and_or_b32
                    b2f[m][r] = __builtin_amdgcn_fmed3f(p, b1f[m][r], b2f[m][r]);
                    b1f[m][r] = fminf(p, b1f[m][r]);
                }
        }
        bc0 = bn0; bc1 = bn1;
        __syncthreads();   // drains prefetch + protects cur reuse
    }

    // merge top-2 across the 16 l4-lanes holding each row; write packed pair
    float2* rowinfo = (float2*)(ws + WS_ROWINFO);
#pragma unroll
    for (int m = 0; m < 4; ++m)
#pragma unroll
        for (int r = 0; r < 4; ++r) {
            float v1 = b1f[m][r], v2 = b2f[m][r];
#pragma unroll
            for (int st = 1; st < 16; st <<= 1) {
                const float o1 = __shfl_xor(v1, st);
                const float o2 = __shfl_xor(v2, st);
                const float mm = fminf(v2, o2);
                v2 = __builtin_amdgcn_fmed3f(v1, o1, mm);
                v1 = fminf(v1, o1);
            }
            if (l4 == 0) {
                const int row = rowbase + m * 16 + kg * 4 + r;
                rowinfo[(size_t)row * 4 + cq] = make_float2(v1, v2);
            }
        }
}

// ===== K5: merge 4 col-quarter partials, flag close rows, hist clear rows =====
__global__ __launch_bounds__(256) void k_flag(float* __restrict__ ws,
                                              float* __restrict__ out) {
    const int r = blockIdx.x * 256 + threadIdx.x;
    const float2* rowinfo = (const float2*)(ws + WS_ROWINFO);
    float2 q = rowinfo[(size_t)r * 4];
    float v1 = q.x, v2 = q.y;
#pragma unroll
    for (int c = 1; c < 4; ++c) {
        q = rowinfo[(size_t)r * 4 + c];
        const float mm = fminf(v2, q.y);
        v2 = __builtin_amdgcn_fmed3f(v1, q.x, mm);
        v1 = fminf(v1, q.x);
    }
    const float v1v = unpackval(v1);
    const int   i1  = (int)(__float_as_uint(v1) & 0xFFFu);
    ws[WS_ROWTHR + r] = v1v + DELTA;
    if (unpackval(v2) - v1v <= DELTA) {
        const int pos = atomicAdd((int*)(ws + WS_NFLAG), 1);
        ((int*)(ws + WS_FLAG))[pos] = r;
    } else {
        out[O_IDX + r] = (float)i1;
        ((int*)(ws + WS_IDX))[r] = i1;
        atomicAdd((int*)(ws + WS_HIST) + i1, 1);
    }
}

// ===== K6: candidate-append mini-GEMM over flagged rows, col-sliced x8 =====
__global__ __launch_bounds__(256) void k_cand(float* __restrict__ ws) {
    extern __shared__ char smem[];      // 2 x 16384
    const int t = threadIdx.x, lane = t & 63, w = t >> 6;
    const int l4 = lane & 15, kg = lane >> 4;
    const char* ximg = (const char*)(ws + WS_XIMG);
    const char* eimg0 = (const char*)(ws + WS_EIMG);
    const float* bvec = ws + WS_BVEC;
    const int* flag = (const int*)(ws + WS_FLAG);
    int* cnt = (int*)(ws + WS_CNT);
    int* cand = (int*)(ws + WS_CAND);
    const int nflag = *(const int*)(ws + WS_NFLAG);
    if (nflag == 0) return;
    const int ntiles = (nflag + 127) >> 7;
    const int nitems = ntiles * 8;

    for (int item = blockIdx.x; item < nitems; item += gridDim.x) {
        const int tile = item >> 3, slice = item & 7;
        const int base = tile * 128 + w * 32;
        const char* eimg = eimg0 + (size_t)slice * 262144;   // 512 cols per slice
        bf16x8 a[2][8];
        int frow[2][4];
        float thr[2][4];
#pragma unroll
        for (int m = 0; m < 2; ++m) {
            const int ia = base + m * 16 + l4;
            const int rowa = flag[ia < nflag ? ia : (nflag - 1)];
            const char* rp = ximg + (size_t)rowa * 512;
#pragma unroll
            for (int ts = 0; ts < 8; ++ts) {
                const int byte = ((kg * 16 + ts * 64) + ((rowa & 15) << 5)) & 511;
                a[m][ts] = *(const bf16x8*)(rp + byte);
            }
#pragma unroll
            for (int r = 0; r < 4; ++r) {
                const int ie = base + m * 16 + kg * 4 + r;
                const bool val = ie < nflag;
                const int rowe = flag[val ? ie : (nflag - 1)];
                frow[m][r] = rowe;
                thr[m][r] = val ? ws[WS_ROWTHR + rowe] : -FLT_MAX;
            }
        }
#pragma unroll
        for (int rr = 0; rr < 4; ++rr) {
            const int off = rr * 4096 + w * 1024;
            GLOAD_LDS16(eimg + off + lane * 16, smem + off);
        }
        __syncthreads();

        for (int ch = 0; ch < 16; ++ch) {
            const char* cur = smem + (ch & 1) * 16384;
            if (ch + 1 < 16) {
                const char* src = eimg + (size_t)(ch + 1) * 16384;
                char* nb = smem + ((ch + 1) & 1) * 16384;
#pragma unroll
                for (int rr = 0; rr < 4; ++rr) {
                    const int off = rr * 4096 + w * 1024;
                    GLOAD_LDS16(src + off + lane * 16, nb + off);
                }
            }
            const float bc0 = bvec[slice * 512 + ch * 32 + l4];
            const float bc1 = bvec[slice * 512 + ch * 32 + 16 + l4];
            f32x4 acc[2][2];
            acc[0][0] = (f32x4){bc0, bc0, bc0, bc0};
            acc[0][1] = (f32x4){bc1, bc1, bc1, bc1};
            acc[1][0] = acc[0][0];
            acc[1][1] = acc[0][1];
#pragma unroll
            for (int ts = 0; ts < 8; ++ts) {
                const int rot = ((kg * 16 + ts * 64) + (l4 << 5)) & 511;
                bf16x8 bfr[2];
#pragma unroll
                for (int n = 0; n < 2; ++n)
                    bfr[n] = *(const bf16x8*)(cur + (n * 16 + l4) * 512 + rot);
#pragma unroll
                for (int m = 0; m < 2; ++m)
#pragma unroll
                    for (int n = 0; n < 2; ++n)
                        acc[m][n] = __builtin_amdgcn_mfma_f32_16x16x32_bf16(a[m][ts], bfr[n], acc[m][n], 0, 0, 0);
            }
#pragma unroll
            for (int n = 0; n < 2; ++n) {
                const int col = slice * 512 + ch * 32 + n * 16 + l4;
#pragma unroll
                for (int m = 0; m < 2; ++m)
#pragma unroll
                    for (int r = 0; r < 4; ++r) {
                        const float s = acc[m][n][r];
                        if (s <= thr[m][r]) {
                            const int rr2 = frow[m][r];
                            const int pos = atomicAdd(&cnt[rr2], 1);
                            if (pos < CAP) cand[(size_t)rr2 * CAP + pos] = col;
                        }
                    }
            }
            __syncthreads();
        }
    }
}

// ===== K7: exact fp32 resolve for flagged rows (+hist) =====
__global__ __launch_bounds__(256) void k_resolve_f(const float* __restrict__ x,
                                                   float* __restrict__ ws,
                                                   float* __restrict__ out) {
    const int t = threadIdx.x, lane = t & 63;
    const int gw = (blockIdx.x * 256 + t) >> 6;     // 1024 waves
    const int nflag = *(const int*)(ws + WS_NFLAG);
    const int* flag = (const int*)(ws + WS_FLAG);
    const int* cnt = (const int*)(ws + WS_CNT);
    const int* cand = (const int*)(ws + WS_CAND);
    const float* eprow = ws + WS_EPROW;
    const float* bvec = ws + WS_BVEC;
    int* idx_int = (int*)(ws + WS_IDX);
    for (int i = gw; i < nflag; i += 1024) {
        const int row = flag[i];
        const float4 xr = ((const float4*)(x + (size_t)row * DDIM))[lane];
        const int n = cnt[row];
        float bestv = FLT_MAX;
        int bestk = KDIM;
        if (n >= 1 && n <= CAP) {
            for (int c = 0; c < n; ++c) {
                const int k = cand[(size_t)row * CAP + c];
                const float4 er = ((const float4*)(eprow + (size_t)k * DDIM))[lane];
                float p = xr.x * er.x + xr.y * er.y + xr.z * er.z + xr.w * er.w;
                p += __shfl_xor(p, 32); p += __shfl_xor(p, 16); p += __shfl_xor(p, 8);
                p += __shfl_xor(p, 4);  p += __shfl_xor(p, 2);  p += __shfl_xor(p, 1);
                const float s = fmaf(-2.f, p, bvec[k]);
                if (s < bestv || (s == bestv && k < bestk)) { bestv = s; bestk = k; }
            }
        } else {   // overflow / safety fallback: exact full scan
            for (int k = 0; k < KDIM; ++k) {
                const float4 er = ((const float4*)(eprow + (size_t)k * DDIM))[lane];
                float p = xr.x * er.x + xr.y * er.y + xr.z * er.z + xr.w * er.w;
                p += __shfl_xor(p, 32); p += __shfl_xor(p, 16); p += __shfl_xor(p, 8);
                p += __shfl_xor(p, 4);  p += __shfl_xor(p, 2);  p += __shfl_xor(p, 1);
                const float s = fmaf(-2.f, p, bvec[k]);
                if (s < bestv || (s == bestv && k < bestk)) { bestv = s; bestk = k; }
            }
        }
        if (lane == 0) {
            out[O_IDX + row] = (float)bestk;
            idx_int[row] = bestk;
            atomicAdd((int*)(ws + WS_HIST) + bestk, 1);
        }
    }
}

// ===== K8: dual prefix sums + segment descriptors + EMA cluster size =====
__global__ __launch_bounds__(256) void k_scan(const float* __restrict__ cs_in,
                                              float* __restrict__ ws) {
    __shared__ int lsum[256], lseg[256];
    __shared__ float redf[256];
    const int t = threadIdx.x;
    const int* hist = (const int*)(ws + WS_HIST);
    int h[16];
    int s = 0, g = 0;
#pragma unroll
    for (int i = 0; i < 16; ++i) {
        h[i] = hist[t * 16 + i];
        s += h[i];
        g += (h[i] + SEG - 1) / SEG;
    }
    lsum[t] = s; lseg[t] = g;
    __syncthreads();
    int v = s, u = g;
    for (int off = 1; off < 256; off <<= 1) {
        const int av = (t >= off) ? lsum[t - off] : 0;
        const int au = (t >= off) ? lseg[t - off] : 0;
        __syncthreads();
        v += av; u += au;
        lsum[t] = v; lseg[t] = u;
        __syncthreads();
    }
    int runs = v - s, rung = u - g;
    int* start = (int*)(ws + WS_START);
    int* fillpos = (int*)(ws + WS_FILLPOS);
    int* segst = (int*)(ws + WS_SEGSTART);
    int* seglist = (int*)(ws + WS_SEGLIST);
    float emapart = 0.f;
#pragma unroll
    for (int i = 0; i < 16; ++i) {
        const int k = t * 16 + i;
        start[k] = runs;
        fillpos[k] = runs;
        segst[k] = rung;
        const int ns = (h[i] + SEG - 1) / SEG;
        for (int j = 0; j < ns; ++j) seglist[rung + j] = (k << 10) | j;
        runs += h[i];
        rung += ns;
        const float ncs = cs_in[k] * DECAYV + (1.0f - DECAYV) * (float)h[i];
        ws[WS_NCSRAW + k] = ncs;
        emapart += ncs;
    }
    if (t == 255) {
        segst[KDIM] = rung;
        *(int*)(ws + WS_NSEG) = rung;
    }
    redf[t] = emapart;
    __syncthreads();
    for (int ss = 128; ss > 0; ss >>= 1) { if (t < ss) redf[t] += redf[t + ss]; __syncthreads(); }
    if (t == 0) ws[WS_NTOT] = redf[0];
}

// ===== K8c: fill per-cluster row lists =====
__global__ __launch_bounds__(256) void k_fill(float* __restrict__ ws) {
    const int r = blockIdx.x * 256 + threadIdx.x;
    const int k = ((const int*)(ws + WS_IDX))[r];
    const int pos = atomicAdd((int*)(ws + WS_FILLPOS) + k, 1);
    ((int*)(ws + WS_ROWLIST))[pos] = r;
}

// ===== K8e: per-segment gather partial sums, float4 + 4-group combine =====
__global__ __launch_bounds__(256) void k_gather_seg(const float* __restrict__ x,
                                                    float* __restrict__ ws) {
    __shared__ float4 ls[4][64];
    const int b = blockIdx.x;
    if (b >= *(const int*)(ws + WS_NSEG)) return;
    const int e = ((const int*)(ws + WS_SEGLIST))[b];
    const int k = e >> 10, j = e & 1023;
    const int base = ((const int*)(ws + WS_START))[k];
    const int n = ((const int*)(ws + WS_HIST))[k];
    const int st = base + j * SEG;
    const int en = min(st + SEG, base + n);
    const int* rowlist = (const int*)(ws + WS_ROWLIST);
    const int t = threadIdx.x, q = t & 63, g = t >> 6;
    const float4* x4 = (const float4*)x;
    float4 s = make_float4(0.f, 0.f, 0.f, 0.f);
    for (int i = st + g; i < en; i += 4) {
        const float4 v = x4[(size_t)rowlist[i] * 64 + q];
        s.x += v.x; s.y += v.y; s.z += v.z; s.w += v.w;
    }
    ls[g][q] = s;
    __syncthreads();
    if (t < 64) {
        const float4 a0 = ls[0][t], a1 = ls[1][t], a2 = ls[2][t], a3 = ls[3][t];
        float4 r;
        r.x = (a0.x + a1.x) + (a2.x + a3.x);
        r.y = (a0.y + a1.y) + (a2.y + a3.y);
        r.z = (a0.z + a1.z) + (a2.z + a3.z);
        r.w = (a0.w + a1.w) + (a2.w + a3.w);
        ((float4*)(ws + WS_DWPART))[(size_t)b * 64 + t] = r;
    }
}

// ===== K9: streaming finalize [K,D] outputs (float4, one wave per k) =====
__global__ __launch_bounds__(64) void k_final(const float* __restrict__ ema_w,
                                              const float* __restrict__ ws,
                                              float* __restrict__ out) {
    const int k = blockIdx.x;   // 4096 blocks
    const int q = threadIdx.x;  // d-quad
    const int* segst = (const int*)(ws + WS_SEGSTART);
    const int ss = segst[k];
    const int ns = segst[k + 1] - ss;
    const float4* dwpart = (const float4*)(ws + WS_DWPART);
    float4 a = make_float4(0.f, 0.f, 0.f, 0.f);
    for (int j = 0; j < ns; ++j) {
        const float4 v = dwpart[(size_t)(ss + j) * 64 + q];
        a.x += v.x; a.y += v.y; a.z += v.z; a.w += v.w;
    }
    const int n = ((const int*)(ws + WS_HIST))[k];
    const float ntot = ws[WS_NTOT];
    const float ncs  = (ws[WS_NCSRAW + k] + 1e-5f) / (ntot + (float)KDIM * 1e-5f) * ntot;
    const float4 mn = ((const float4*)(ws + WS_MEAN))[q];
    const float4 rs = ((const float4*)(ws + WS_RSTD))[q];
    const float4 nrv = ((const float4*)(ws + WS_NRVAR))[q];
    const float4 nrm = ((const float4*)(ws + WS_NRMEAN))[q];
    const float4 ew = ((const float4*)ema_w)[(size_t)k * 64 + q];
    const float fn = (float)n;
    float4 nwv, nembv, eov;
    nwv.x = ew.x * DECAYV + (1.f - DECAYV) * ((a.x - fn * mn.x) * rs.x);
    nwv.y = ew.y * DECAYV + (1.f - DECAYV) * ((a.y - fn * mn.y) * rs.y);
    nwv.z = ew.z * DECAYV + (1.f - DECAYV) * ((a.z - fn * mn.z) * rs.z);
    nwv.w = ew.w * DECAYV + (1.f - DECAYV) * ((a.w - fn * mn.w) * rs.w);
    const float inv = 1.0f / ncs;
    nembv.x = nwv.x * inv; nembv.y = nwv.y * inv;
    nembv.z = nwv.z * inv; nembv.w = nwv.w * inv;
    eov.x = nembv.x * sqrtf(nrv.x + EPSV) + nrm.x;
    eov.y = nembv.y * sqrtf(nrv.y + EPSV) + nrm.y;
    eov.z = nembv.z * sqrtf(nrv.z + EPSV) + nrm.z;
    eov.w = nembv.w * sqrtf(nrv.w + EPSV) + nrm.w;
    ((float4*)(out + O_EMB))[(size_t)k * 64 + q]  = nembv;
    ((float4*)(out + O_EOUT))[(size_t)k * 64 + q] = eov;
    ((float4*)(out + O_EMAW))[(size_t)k * 64 + q] = nwv;
    if (q == 0) out[O_CS + k] = ncs;
}

// ===== launcher =====
extern "C" void kernel_launch(void* const* d_in, const int* in_sizes, int n_in,
                              void* d_out, int out_size, void* d_ws, size_t ws_size,
                              hipStream_t stream) {
    const float* x     = (const float*)d_in[0];
    const float* emb   = (const float*)d_in[1];
    const float* cs    = (const float*)d_in[2];
    const float* ema_w = (const float*)d_in[3];
    const float* rmean = (const float*)d_in[4];
    const float* rvar  = (const float*)d_in[5];
    float* out = (float*)d_out;
    float* ws  = (float*)d_ws;

    // zero cnt + nflag + hist (contiguous at ws base, ~280 KB)
    hipMemsetAsync(ws, 0, WS_ZEND * sizeof(float), stream);

    k_bnpack<<<512, 256, 0, stream>>>(x, ws);
    k_bn_mid<<<256, 256, 0, stream>>>(ws);
    k_bn_final<<<1, 256, 0, stream>>>(rmean, rvar, ws, out);
    k_eprime<<<KDIM / 4, 256, 0, stream>>>(emb, ws);

    constexpr int LDSB = 32768;
    k_gemm_min<<<1024, 256, LDSB, stream>>>(ws);
    k_flag<<<NROWS / 256, 256, 0, stream>>>(ws, out);
    k_cand<<<512, 256, LDSB, stream>>>(ws);
    k_resolve_f<<<256, 256, 0, stream>>>(x, ws, out);

    k_scan<<<1, 256, 0, stream>>>(cs, ws);
    k_fill<<<NROWS / 256, 256, 0, stream>>>(ws);
    k_gather_seg<<<4608, 256, 0, stream>>>(x, ws);
    k_final<<<KDIM, 64, 0, stream>>>(ema_w, ws, out);
}